// Round 2
// baseline (593.754 us; speedup 1.0000x reference)
//
#include <hip/hip_runtime.h>

// ---------------------------------------------------------------------------
// LlamaDifferentialAttentionBase on MI355X (gfx950)
// B=1, S=2048, HID=2048, H=32, D=64. All inputs fp32; output fp32.
// R2: diff_attn -> 4 waves/block splitting kv range (barrier-free k-loop,
//     private P buffers, LDS combine); GEMMs -> global_load_lds (m97 style).
// ---------------------------------------------------------------------------

typedef __bf16 bf16;
typedef __bf16 bf16x4 __attribute__((ext_vector_type(4)));
typedef __bf16 bf16x8 __attribute__((ext_vector_type(8)));
typedef float  f32x4  __attribute__((ext_vector_type(4)));

#define MFMA(a, b, c) __builtin_amdgcn_mfma_f32_16x16x32_bf16((a), (b), (c), 0, 0, 0)

#define S_LEN   2048
#define HID_DIM 2048
#define NHEAD   32
#define HD      64
#define QKV_N   10240                 // 4096 (q) + 4096 (k) + 2048 (v)
#define LAM_INIT 0.7836057665316245f  // 0.8 - 0.6*exp(-0.3*12)
#define ONE_MINUS_LAM_INIT 0.21639423346837553f
#define QSCALE  0.18033688011112042f  // (1/sqrt(64)) * log2(e)
#define RMS_EPS 1e-6f

// async global->LDS, 16B per lane; LDS dest = wave-uniform base + lane*16
__device__ __forceinline__ void gld16(const void* g, void* l) {
    __builtin_amdgcn_global_load_lds(
        (const __attribute__((address_space(1))) void*)g,
        (__attribute__((address_space(3))) void*)l, 16, 0, 0);
}

// ---------------------------------------------------------------------------
// fp32 -> bf16, float4-vectorized
// ---------------------------------------------------------------------------
__global__ void cvt_f32_bf16(const float* __restrict__ src, bf16* __restrict__ dst, int n) {
    int i = (blockIdx.x * 256 + threadIdx.x) * 4;
    if (i + 3 < n) {
        float4 v = *(const float4*)(src + i);
        bf16x4 o = { (bf16)v.x, (bf16)v.y, (bf16)v.z, (bf16)v.w };
        *(bf16x4*)(dst + i) = o;
    }
}

// ---------------------------------------------------------------------------
// lambda scalar
// ---------------------------------------------------------------------------
__global__ void lam_kernel(const float* __restrict__ lq1, const float* __restrict__ lk1,
                           const float* __restrict__ lq2, const float* __restrict__ lk2,
                           float* __restrict__ out) {
    int t = threadIdx.x;
    float a = lq1[t] * lk1[t];
    float b = lq2[t] * lk2[t];
    #pragma unroll
    for (int off = 32; off > 0; off >>= 1) {
        a += __shfl_xor(a, off, 64);
        b += __shfl_xor(b, off, 64);
    }
    if (t == 0) out[0] = expf(a) - expf(b) + LAM_INIT;
}

// ---------------------------------------------------------------------------
// GEMM: C[M,N] = A[M,K] * B[N,K]^T, 128x128 tile, BK=32, 4 waves,
// m97-style global_load_lds staging (2-barrier K-loop).
// ---------------------------------------------------------------------------
template<int OUT_BF16>
__global__ __launch_bounds__(256, 2)
void gemm_bt(const bf16* __restrict__ A, const bf16* __restrict__ B,
             void* __restrict__ Cout, int M, int N, int K) {
    __shared__ __align__(16) bf16 As[128 * 32];
    __shared__ __align__(16) bf16 Bs[128 * 32];
    const int tid  = threadIdx.x;
    const int wave = tid >> 6, lane = tid & 63;
    const int wm = wave >> 1, wn = wave & 1;
    const int l = lane & 15, quad = lane >> 4;
    const int m0 = blockIdx.y * 128, n0 = blockIdx.x * 128;

    f32x4 acc[4][4];
    #pragma unroll
    for (int i = 0; i < 4; ++i)
        #pragma unroll
        for (int j = 0; j < 4; ++j) acc[i][j] = (f32x4){0.f, 0.f, 0.f, 0.f};

    // staging geometry: thread stages 16B at LDS elem offset tid*8 (+2048),
    // from global row r0 (r0+64), col c0
    const int r0 = tid >> 2, c0 = (tid & 3) * 8;
    const bf16* Ag = A + (size_t)(m0 + r0) * K + c0;
    const bf16* Bg = B + (size_t)(n0 + r0) * K + c0;
    bf16* As0 = As + tid * 8;
    bf16* Bs0 = Bs + tid * 8;

    for (int kt = 0; kt < K; kt += 32) {
        __syncthreads();
        gld16(Ag + kt, As0);
        gld16(Ag + (size_t)64 * K + kt, As0 + 2048);
        gld16(Bg + kt, Bs0);
        gld16(Bg + (size_t)64 * K + kt, Bs0 + 2048);
        __syncthreads();   // compiler drains vmcnt before s_barrier

        bf16x8 af[4], bfr[4];
        #pragma unroll
        for (int mi = 0; mi < 4; ++mi)
            af[mi] = *(const bf16x8*)(As + (wm * 64 + mi * 16 + l) * 32 + quad * 8);
        #pragma unroll
        for (int ni = 0; ni < 4; ++ni)
            bfr[ni] = *(const bf16x8*)(Bs + (wn * 64 + ni * 16 + l) * 32 + quad * 8);
        #pragma unroll
        for (int mi = 0; mi < 4; ++mi)
            #pragma unroll
            for (int ni = 0; ni < 4; ++ni)
                acc[mi][ni] = MFMA(af[mi], bfr[ni], acc[mi][ni]);
    }

    // C/D layout: row = quad*4 + r, col = lane&15
    #pragma unroll
    for (int mi = 0; mi < 4; ++mi)
        #pragma unroll
        for (int ni = 0; ni < 4; ++ni)
            #pragma unroll
            for (int r = 0; r < 4; ++r) {
                const int row = m0 + wm * 64 + mi * 16 + quad * 4 + r;
                const int col = n0 + wn * 64 + ni * 16 + l;
                const float v = acc[mi][ni][r];
                if (OUT_BF16) ((bf16*)Cout)[(size_t)row * N + col] = (bf16)v;
                else          ((float*)Cout)[(size_t)row * N + col] = v;
            }
}

// ---------------------------------------------------------------------------
// RoPE + head split (unchanged from R1)
// ---------------------------------------------------------------------------
__global__ __launch_bounds__(256)
void rope_split(const bf16* __restrict__ qkv,
                bf16* __restrict__ Q1, bf16* __restrict__ K1,
                bf16* __restrict__ Q2, bf16* __restrict__ K2,
                bf16* __restrict__ Vt) {
    const int h = blockIdx.y;
    const int s0 = blockIdx.x * 64;
    const int t = threadIdx.x;
    const int d = t & 63, sr = t >> 6;
    __shared__ __align__(16) bf16 vt_lds[64][72];

    const int i = d & 31;
    const float invf = exp2f(-(float)i * 0.4152410118609203f);
    const float sign = (d < 32) ? -1.0f : 1.0f;

    for (int it = 0; it < 16; ++it) {
        const int s = s0 + it * 4 + sr;
        const bf16* row = qkv + (size_t)s * QKV_N;
        const int cb  = h * 64 + d;
        const int cbo = h * 64 + (d ^ 32);
        const float ang = (float)s * invf;
        const float cs = cosf(ang), sn = sinf(ang);
        const float q1v = (float)row[cb],         q1o = (float)row[cbo];
        const float q2v = (float)row[2048 + cb],  q2o = (float)row[2048 + cbo];
        const float k1v = (float)row[4096 + cb],  k1o = (float)row[4096 + cbo];
        const float k2v = (float)row[6144 + cb],  k2o = (float)row[6144 + cbo];
        const float vv  = (float)row[8192 + cb];
        const size_t o = ((size_t)h * S_LEN + s) * HD + d;
        Q1[o] = (bf16)((q1v * cs + sign * q1o * sn) * QSCALE);
        Q2[o] = (bf16)((q2v * cs + sign * q2o * sn) * QSCALE);
        K1[o] = (bf16)(k1v * cs + sign * k1o * sn);
        K2[o] = (bf16)(k2v * cs + sign * k2o * sn);
        vt_lds[d][it * 4 + sr] = (bf16)vv;
    }
    __syncthreads();
    const int dd = t >> 2, cg = t & 3;
    bf16x8 w0 = *(const bf16x8*)(&vt_lds[dd][cg * 16]);
    bf16x8 w1 = *(const bf16x8*)(&vt_lds[dd][cg * 16 + 8]);
    bf16* dst = Vt + ((size_t)h * HD + dd) * S_LEN + s0 + cg * 16;
    *(bf16x8*)(dst)     = w0;
    *(bf16x8*)(dst + 8) = w1;
}

// ---------------------------------------------------------------------------
// Differential flash attention, R2 structure:
//  - 256-thread block = 4 waves, all on the SAME 32 q-rows of one head.
//  - Wave w handles kv tiles t = w, w+4, ... (round robin). No barriers in
//    the k-loop: each wave has a private P slice; wave-internal LDS
//    visibility via s_waitcnt lgkmcnt(0) (DS pipe is in-order per wave).
//  - Epilogue: combine 4 partial O / denominators through LDS (reusing the
//    P region), then per-thread normalize + diff + RMSNorm + store.
//  - qb reversed so the longest (most kv tiles) blocks dispatch first.
// ---------------------------------------------------------------------------
__global__ __launch_bounds__(256, 4)
void diff_attn(const bf16* __restrict__ Q1, const bf16* __restrict__ K1,
               const bf16* __restrict__ Q2, const bf16* __restrict__ K2,
               const bf16* __restrict__ Vt, const float* __restrict__ lam_p,
               const float* __restrict__ subln_w, bf16* __restrict__ attn_out) {
    const int h  = blockIdx.y;
    const int qb = ((int)gridDim.x - 1) - (int)blockIdx.x;  // heavy first
    const int q0 = qb * 32;
    const int tid = threadIdx.x;
    const int wave = tid >> 6, lane = tid & 63;
    const int l = lane & 15, quad = lane >> 4;

    // [wave][2 streams][32 rows x 72] bf16 = 4*9216 B
    __shared__ __align__(16) char smem[36864];
    bf16* P1 = (bf16*)(smem + wave * 9216);
    bf16* P2 = (bf16*)(smem + wave * 9216 + 4608);

    const bf16* Q1h = Q1 + ((size_t)h * S_LEN + q0) * HD;
    const bf16* Q2h = Q2 + ((size_t)h * S_LEN + q0) * HD;
    const bf16* K1h = K1 + (size_t)h * S_LEN * HD;
    const bf16* K2h = K2 + (size_t)h * S_LEN * HD;
    const bf16* Vth = Vt + (size_t)h * HD * S_LEN;

    // Q as B-operand fragments (same data across all 4 waves -> L1 hits)
    bf16x8 q1b[2][2], q2b[2][2];
    #pragma unroll
    for (int ni = 0; ni < 2; ++ni)
        #pragma unroll
        for (int ks = 0; ks < 2; ++ks) {
            q1b[ni][ks] = *(const bf16x8*)(Q1h + (ni * 16 + l) * HD + ks * 32 + quad * 8);
            q2b[ni][ks] = *(const bf16x8*)(Q2h + (ni * 16 + l) * HD + ks * 32 + quad * 8);
        }

    f32x4 O1[2][4], O2[2][4];
    #pragma unroll
    for (int mi = 0; mi < 2; ++mi)
        #pragma unroll
        for (int ni = 0; ni < 4; ++ni) {
            O1[mi][ni] = (f32x4){0.f, 0.f, 0.f, 0.f};
            O2[mi][ni] = (f32x4){0.f, 0.f, 0.f, 0.f};
        }
    float cs1[2] = {0.f, 0.f}, cs2[2] = {0.f, 0.f};

    const int nkt = (q0 >> 6) + 1;
    for (int kt = wave; kt < nkt; kt += 4) {
        const int kv0 = kt * 64;
        const bool maskt = (kt == nkt - 1);

        // WAR guard: previous PV reads of this wave's P must be done
        asm volatile("s_waitcnt lgkmcnt(0)" ::: "memory");

        // ---- scores stream 1: S^T[kv][m] ----
        #pragma unroll
        for (int mi = 0; mi < 4; ++mi) {
            const bf16* krow = K1h + (size_t)(kv0 + mi * 16 + l) * HD;
            bf16x8 ka0 = *(const bf16x8*)(krow + quad * 8);
            bf16x8 ka1 = *(const bf16x8*)(krow + 32 + quad * 8);
            #pragma unroll
            for (int ni = 0; ni < 2; ++ni) {
                f32x4 c = (f32x4){0.f, 0.f, 0.f, 0.f};
                c = MFMA(ka0, q1b[ni][0], c);
                c = MFMA(ka1, q1b[ni][1], c);
                const int kvb  = kv0 + mi * 16 + quad * 4;
                const int mcol = q0 + ni * 16 + l;
                bf16x4 pk;
                float lsum = 0.f;
                #pragma unroll
                for (int r = 0; r < 4; ++r) {
                    float p = __builtin_amdgcn_exp2f(c[r]);
                    if (maskt && (kvb + r > mcol)) p = 0.f;
                    lsum += p;
                    pk[r] = (bf16)p;
                }
                cs1[ni] += lsum;
                *(bf16x4*)(P1 + (ni * 16 + l) * 72 + mi * 16 + quad * 4) = pk;
            }
        }
        // ---- scores stream 2 ----
        #pragma unroll
        for (int mi = 0; mi < 4; ++mi) {
            const bf16* krow = K2h + (size_t)(kv0 + mi * 16 + l) * HD;
            bf16x8 ka0 = *(const bf16x8*)(krow + quad * 8);
            bf16x8 ka1 = *(const bf16x8*)(krow + 32 + quad * 8);
            #pragma unroll
            for (int ni = 0; ni < 2; ++ni) {
                f32x4 c = (f32x4){0.f, 0.f, 0.f, 0.f};
                c = MFMA(ka0, q2b[ni][0], c);
                c = MFMA(ka1, q2b[ni][1], c);
                const int kvb  = kv0 + mi * 16 + quad * 4;
                const int mcol = q0 + ni * 16 + l;
                bf16x4 pk;
                float lsum = 0.f;
                #pragma unroll
                for (int r = 0; r < 4; ++r) {
                    float p = __builtin_amdgcn_exp2f(c[r]);
                    if (maskt && (kvb + r > mcol)) p = 0.f;
                    lsum += p;
                    pk[r] = (bf16)p;
                }
                cs2[ni] += lsum;
                *(bf16x4*)(P2 + (ni * 16 + l) * 72 + mi * 16 + quad * 4) = pk;
            }
        }

        // make this wave's P writes visible to its own cross-lane reads
        asm volatile("s_waitcnt lgkmcnt(0)" ::: "memory");

        // ---- PV: O[m][d] += P[m][kp] * Vt[d][kp]^T ----
        #pragma unroll
        for (int ks = 0; ks < 2; ++ks) {
            bf16x8 pa1[2], pa2[2];
            #pragma unroll
            for (int mi = 0; mi < 2; ++mi) {
                pa1[mi] = *(const bf16x8*)(P1 + (mi * 16 + l) * 72 + ks * 32 + quad * 8);
                pa2[mi] = *(const bf16x8*)(P2 + (mi * 16 + l) * 72 + ks * 32 + quad * 8);
            }
            #pragma unroll
            for (int ni = 0; ni < 4; ++ni) {
                bf16x8 vb = *(const bf16x8*)(Vth + (size_t)(ni * 16 + l) * S_LEN + kv0 + ks * 32 + quad * 8);
                #pragma unroll
                for (int mi = 0; mi < 2; ++mi) {
                    O1[mi][ni] = MFMA(pa1[mi], vb, O1[mi][ni]);
                    O2[mi][ni] = MFMA(pa2[mi], vb, O2[mi][ni]);
                }
            }
        }
    }

    // ---------------- epilogue: combine 4 waves ----------------
    __syncthreads();            // all P buffers dead; smem reusable
    float* Ob1  = (float*)smem;             // [32][64]  8 KB
    float* Ob2  = (float*)(smem + 8192);    // [32][64]  8 KB
    float* cbs1 = (float*)(smem + 16384);   // [4][2][64] 2 KB
    float* cbs2 = (float*)(smem + 18432);   // [4][2][64] 2 KB

    cbs1[wave * 128 + lane]      = cs1[0];
    cbs1[wave * 128 + 64 + lane] = cs1[1];
    cbs2[wave * 128 + lane]      = cs2[0];
    cbs2[wave * 128 + 64 + lane] = cs2[1];

    if (wave == 0) {
        #pragma unroll
        for (int mi = 0; mi < 2; ++mi)
            #pragma unroll
            for (int ni = 0; ni < 4; ++ni)
                #pragma unroll
                for (int r = 0; r < 4; ++r) {
                    const int idx = (mi * 16 + quad * 4 + r) * 64 + ni * 16 + l;
                    Ob1[idx] = O1[mi][ni][r];
                    Ob2[idx] = O2[mi][ni][r];
                }
    }
    __syncthreads();
    #pragma unroll
    for (int w = 1; w < 4; ++w) {
        if (wave == w) {
            #pragma unroll
            for (int mi = 0; mi < 2; ++mi)
                #pragma unroll
                for (int ni = 0; ni < 4; ++ni)
                    #pragma unroll
                    for (int r = 0; r < 4; ++r) {
                        const int idx = (mi * 16 + quad * 4 + r) * 64 + ni * 16 + l;
                        Ob1[idx] += O1[mi][ni][r];
                        Ob2[idx] += O2[mi][ni][r];
                    }
        }
        __syncthreads();
    }

    // per-thread final: row = tid>>3 (0..31), cols (tid&7)*8 .. +8
    const float lam = lam_p[0];
    const int row = tid >> 3;
    const int cb8 = (tid & 7) * 8;
    const int ni_r = row >> 4, l_r = row & 15;
    float den1 = 0.f, den2 = 0.f;
    #pragma unroll
    for (int w = 0; w < 4; ++w)
        #pragma unroll
        for (int q = 0; q < 4; ++q) {
            den1 += cbs1[w * 128 + ni_r * 64 + q * 16 + l_r];
            den2 += cbs2[w * 128 + ni_r * 64 + q * 16 + l_r];
        }
    const float inv1 = 1.0f / den1;
    const float inv2 = lam / den2;

    float v[8]; float ssq = 0.f;
    #pragma unroll
    for (int j = 0; j < 8; ++j) {
        const float x = Ob1[row * 64 + cb8 + j] * inv1 - Ob2[row * 64 + cb8 + j] * inv2;
        v[j] = x;
        ssq += x * x;
    }
    ssq += __shfl_xor(ssq, 1, 64);
    ssq += __shfl_xor(ssq, 2, 64);
    ssq += __shfl_xor(ssq, 4, 64);
    const float rms = rsqrtf(ssq * (1.0f / 64.0f) + RMS_EPS) * ONE_MINUS_LAM_INIT;

    bf16x8 ov;
    #pragma unroll
    for (int j = 0; j < 8; ++j)
        ov[j] = (bf16)(v[j] * rms * subln_w[cb8 + j]);
    *(bf16x8*)(attn_out + (size_t)(q0 + row) * HID_DIM + h * 64 + cb8) = ov;
}

// ---------------------------------------------------------------------------
// Workspace layout: see R1 (unchanged), total ~151 MB
// ---------------------------------------------------------------------------
extern "C" void kernel_launch(void* const* d_in, const int* in_sizes, int n_in,
                              void* d_out, int out_size, void* d_ws, size_t ws_size,
                              hipStream_t stream) {
    const float* hs  = (const float*)d_in[0];
    const float* Wq  = (const float*)d_in[1];
    const float* Wk  = (const float*)d_in[2];
    const float* Wv  = (const float*)d_in[3];
    const float* Wo  = (const float*)d_in[4];
    const float* lq1 = (const float*)d_in[5];
    const float* lk1 = (const float*)d_in[6];
    const float* lq2 = (const float*)d_in[7];
    const float* lk2 = (const float*)d_in[8];
    const float* slw = (const float*)d_in[9];

    if (ws_size < 151000000u) return;

    char* ws = (char*)d_ws;
    bf16*  hsb  = (bf16*)(ws);
    bf16*  Wb   = (bf16*)(ws + 8388608);
    bf16*  Wob  = (bf16*)(ws + 50331648);
    bf16*  qkv  = (bf16*)(ws + 58720256);
    bf16*  Q1b  = (bf16*)(ws + 100663296);
    bf16*  K1b  = (bf16*)(ws + 109051904);
    bf16*  Q2b  = (bf16*)(ws + 117440512);
    bf16*  K2b  = (bf16*)(ws + 125829120);
    bf16*  Vtb  = (bf16*)(ws + 134217728);
    bf16*  abuf = (bf16*)(ws + 142606336);
    float* lamp = (float*)(ws + 150994944);

    cvt_f32_bf16<<<4096, 256, 0, stream>>>(hs, hsb, 4194304);
    cvt_f32_bf16<<<8192, 256, 0, stream>>>(Wq, Wb, 8388608);
    cvt_f32_bf16<<<8192, 256, 0, stream>>>(Wk, Wb + 8388608, 8388608);
    cvt_f32_bf16<<<4096, 256, 0, stream>>>(Wv, Wb + 16777216, 4194304);
    cvt_f32_bf16<<<4096, 256, 0, stream>>>(Wo, Wob, 4194304);
    lam_kernel<<<1, 64, 0, stream>>>(lq1, lk1, lq2, lk2, lamp);

    gemm_bt<1><<<dim3(QKV_N / 128, S_LEN / 128), 256, 0, stream>>>(
        hsb, Wb, qkv, S_LEN, QKV_N, HID_DIM);

    rope_split<<<dim3(S_LEN / 64, NHEAD), 256, 0, stream>>>(qkv, Q1b, K1b, Q2b, K2b, Vtb);

    diff_attn<<<dim3(S_LEN / 32, NHEAD), 256, 0, stream>>>(
        Q1b, K1b, Q2b, K2b, Vtb, lamp, slw, abuf);

    gemm_bt<0><<<dim3(HID_DIM / 128, S_LEN / 128), 256, 0, stream>>>(
        abuf, Wob, d_out, S_LEN, HID_DIM, HID_DIM);
}

// Round 3
// 549.731 us; speedup vs baseline: 1.0801x; 1.0801x over previous
//
#include <hip/hip_runtime.h>

// ---------------------------------------------------------------------------
// LlamaDifferentialAttentionBase on MI355X (gfx950)
// B=1, S=2048, HID=2048, H=32, D=64. All inputs fp32; output fp32.
// R3: diff_attn -> 4 waves/block; wave pair = one attention stream; pair
//     splits kv tiles by parity. Per-wave regs ~halved vs R2 (no spill at
//     launch_bounds(256,4)). Barrier-free k-loop, LDS combine epilogue.
// ---------------------------------------------------------------------------

typedef __bf16 bf16;
typedef __bf16 bf16x4 __attribute__((ext_vector_type(4)));
typedef __bf16 bf16x8 __attribute__((ext_vector_type(8)));
typedef float  f32x4  __attribute__((ext_vector_type(4)));

#define MFMA(a, b, c) __builtin_amdgcn_mfma_f32_16x16x32_bf16((a), (b), (c), 0, 0, 0)

#define S_LEN   2048
#define HID_DIM 2048
#define NHEAD   32
#define HD      64
#define QKV_N   10240                 // 4096 (q) + 4096 (k) + 2048 (v)
#define LAM_INIT 0.7836057665316245f  // 0.8 - 0.6*exp(-0.3*12)
#define ONE_MINUS_LAM_INIT 0.21639423346837553f
#define QSCALE  0.18033688011112042f  // (1/sqrt(64)) * log2(e)
#define RMS_EPS 1e-6f

// async global->LDS, 16B per lane; LDS dest = wave-uniform base + lane*16
__device__ __forceinline__ void gld16(const void* g, void* l) {
    __builtin_amdgcn_global_load_lds(
        (const __attribute__((address_space(1))) void*)g,
        (__attribute__((address_space(3))) void*)l, 16, 0, 0);
}

// ---------------------------------------------------------------------------
// fp32 -> bf16, float4-vectorized
// ---------------------------------------------------------------------------
__global__ void cvt_f32_bf16(const float* __restrict__ src, bf16* __restrict__ dst, int n) {
    int i = (blockIdx.x * 256 + threadIdx.x) * 4;
    if (i + 3 < n) {
        float4 v = *(const float4*)(src + i);
        bf16x4 o = { (bf16)v.x, (bf16)v.y, (bf16)v.z, (bf16)v.w };
        *(bf16x4*)(dst + i) = o;
    }
}

// ---------------------------------------------------------------------------
// lambda scalar
// ---------------------------------------------------------------------------
__global__ void lam_kernel(const float* __restrict__ lq1, const float* __restrict__ lk1,
                           const float* __restrict__ lq2, const float* __restrict__ lk2,
                           float* __restrict__ out) {
    int t = threadIdx.x;
    float a = lq1[t] * lk1[t];
    float b = lq2[t] * lk2[t];
    #pragma unroll
    for (int off = 32; off > 0; off >>= 1) {
        a += __shfl_xor(a, off, 64);
        b += __shfl_xor(b, off, 64);
    }
    if (t == 0) out[0] = expf(a) - expf(b) + LAM_INIT;
}

// ---------------------------------------------------------------------------
// GEMM: C[M,N] = A[M,K] * B[N,K]^T, 128x128 tile, BK=32, 4 waves,
// m97-style global_load_lds staging (2-barrier K-loop).
// ---------------------------------------------------------------------------
template<int OUT_BF16>
__global__ __launch_bounds__(256, 2)
void gemm_bt(const bf16* __restrict__ A, const bf16* __restrict__ B,
             void* __restrict__ Cout, int M, int N, int K) {
    __shared__ __align__(16) bf16 As[128 * 32];
    __shared__ __align__(16) bf16 Bs[128 * 32];
    const int tid  = threadIdx.x;
    const int wave = tid >> 6, lane = tid & 63;
    const int wm = wave >> 1, wn = wave & 1;
    const int l = lane & 15, quad = lane >> 4;
    const int m0 = blockIdx.y * 128, n0 = blockIdx.x * 128;

    f32x4 acc[4][4];
    #pragma unroll
    for (int i = 0; i < 4; ++i)
        #pragma unroll
        for (int j = 0; j < 4; ++j) acc[i][j] = (f32x4){0.f, 0.f, 0.f, 0.f};

    const int r0 = tid >> 2, c0 = (tid & 3) * 8;
    const bf16* Ag = A + (size_t)(m0 + r0) * K + c0;
    const bf16* Bg = B + (size_t)(n0 + r0) * K + c0;
    bf16* As0 = As + tid * 8;
    bf16* Bs0 = Bs + tid * 8;

    for (int kt = 0; kt < K; kt += 32) {
        __syncthreads();
        gld16(Ag + kt, As0);
        gld16(Ag + (size_t)64 * K + kt, As0 + 2048);
        gld16(Bg + kt, Bs0);
        gld16(Bg + (size_t)64 * K + kt, Bs0 + 2048);
        __syncthreads();   // compiler drains vmcnt before s_barrier

        bf16x8 af[4], bfr[4];
        #pragma unroll
        for (int mi = 0; mi < 4; ++mi)
            af[mi] = *(const bf16x8*)(As + (wm * 64 + mi * 16 + l) * 32 + quad * 8);
        #pragma unroll
        for (int ni = 0; ni < 4; ++ni)
            bfr[ni] = *(const bf16x8*)(Bs + (wn * 64 + ni * 16 + l) * 32 + quad * 8);
        #pragma unroll
        for (int mi = 0; mi < 4; ++mi)
            #pragma unroll
            for (int ni = 0; ni < 4; ++ni)
                acc[mi][ni] = MFMA(af[mi], bfr[ni], acc[mi][ni]);
    }

    // C/D layout: row = quad*4 + r, col = lane&15
    #pragma unroll
    for (int mi = 0; mi < 4; ++mi)
        #pragma unroll
        for (int ni = 0; ni < 4; ++ni)
            #pragma unroll
            for (int r = 0; r < 4; ++r) {
                const int row = m0 + wm * 64 + mi * 16 + quad * 4 + r;
                const int col = n0 + wn * 64 + ni * 16 + l;
                const float v = acc[mi][ni][r];
                if (OUT_BF16) ((bf16*)Cout)[(size_t)row * N + col] = (bf16)v;
                else          ((float*)Cout)[(size_t)row * N + col] = v;
            }
}

// ---------------------------------------------------------------------------
// RoPE + head split (unchanged)
// ---------------------------------------------------------------------------
__global__ __launch_bounds__(256)
void rope_split(const bf16* __restrict__ qkv,
                bf16* __restrict__ Q1, bf16* __restrict__ K1,
                bf16* __restrict__ Q2, bf16* __restrict__ K2,
                bf16* __restrict__ Vt) {
    const int h = blockIdx.y;
    const int s0 = blockIdx.x * 64;
    const int t = threadIdx.x;
    const int d = t & 63, sr = t >> 6;
    __shared__ __align__(16) bf16 vt_lds[64][72];

    const int i = d & 31;
    const float invf = exp2f(-(float)i * 0.4152410118609203f);
    const float sign = (d < 32) ? -1.0f : 1.0f;

    for (int it = 0; it < 16; ++it) {
        const int s = s0 + it * 4 + sr;
        const bf16* row = qkv + (size_t)s * QKV_N;
        const int cb  = h * 64 + d;
        const int cbo = h * 64 + (d ^ 32);
        const float ang = (float)s * invf;
        const float cs = cosf(ang), sn = sinf(ang);
        const float q1v = (float)row[cb],         q1o = (float)row[cbo];
        const float q2v = (float)row[2048 + cb],  q2o = (float)row[2048 + cbo];
        const float k1v = (float)row[4096 + cb],  k1o = (float)row[4096 + cbo];
        const float k2v = (float)row[6144 + cb],  k2o = (float)row[6144 + cbo];
        const float vv  = (float)row[8192 + cb];
        const size_t o = ((size_t)h * S_LEN + s) * HD + d;
        Q1[o] = (bf16)((q1v * cs + sign * q1o * sn) * QSCALE);
        Q2[o] = (bf16)((q2v * cs + sign * q2o * sn) * QSCALE);
        K1[o] = (bf16)(k1v * cs + sign * k1o * sn);
        K2[o] = (bf16)(k2v * cs + sign * k2o * sn);
        vt_lds[d][it * 4 + sr] = (bf16)vv;
    }
    __syncthreads();
    const int dd = t >> 2, cg = t & 3;
    bf16x8 w0 = *(const bf16x8*)(&vt_lds[dd][cg * 16]);
    bf16x8 w1 = *(const bf16x8*)(&vt_lds[dd][cg * 16 + 8]);
    bf16* dst = Vt + ((size_t)h * HD + dd) * S_LEN + s0 + cg * 16;
    *(bf16x8*)(dst)     = w0;
    *(bf16x8*)(dst + 8) = w1;
}

// ---------------------------------------------------------------------------
// Differential flash attention, R3 structure:
//  - 256-thread block = 4 waves on the SAME 32 q-rows of one head.
//  - Waves 0,1 compute stream 1; waves 2,3 compute stream 2 (halves the
//    per-wave register footprint vs R2: 32 AGPR acc + 16 VGPR q-frags).
//  - Within a pair, kv tiles split by parity. No barriers in the k-loop:
//    private P slice per wave; wave-internal LDS visibility via
//    s_waitcnt lgkmcnt(0).
//  - Epilogue: 2-phase partial-O combine in LDS, then per-thread
//    normalize + diff + RMSNorm + store.
// ---------------------------------------------------------------------------
__global__ __launch_bounds__(256, 4)
void diff_attn(const bf16* __restrict__ Q1, const bf16* __restrict__ K1,
               const bf16* __restrict__ Q2, const bf16* __restrict__ K2,
               const bf16* __restrict__ Vt, const float* __restrict__ lam_p,
               const float* __restrict__ subln_w, bf16* __restrict__ attn_out) {
    const int h  = blockIdx.y;
    const int qb = ((int)gridDim.x - 1) - (int)blockIdx.x;  // heavy first
    const int q0 = qb * 32;
    const int tid = threadIdx.x;
    const int wave = tid >> 6, lane = tid & 63;
    const int sid = wave >> 1, sub = wave & 1;              // stream, kv parity
    const int l = lane & 15, quad = lane >> 4;

    __shared__ __align__(16) char smem[18432];              // 4 x [32][72] bf16
    bf16* Pw = (bf16*)(smem + wave * 4608);

    const bf16* Qh  = (sid == 0 ? Q1 : Q2) + ((size_t)h * S_LEN + q0) * HD;
    const bf16* Kh  = (sid == 0 ? K1 : K2) + (size_t)h * S_LEN * HD;
    const bf16* Vth = Vt + (size_t)h * HD * S_LEN;

    // Q as B-operand fragments: B[n = ni*16+l][k = ks*32+quad*8+j]
    bf16x8 qf[2][2];
    #pragma unroll
    for (int ni = 0; ni < 2; ++ni)
        #pragma unroll
        for (int ks = 0; ks < 2; ++ks)
            qf[ni][ks] = *(const bf16x8*)(Qh + (ni * 16 + l) * HD + ks * 32 + quad * 8);

    f32x4 O[2][4];
    #pragma unroll
    for (int mi = 0; mi < 2; ++mi)
        #pragma unroll
        for (int ni = 0; ni < 4; ++ni)
            O[mi][ni] = (f32x4){0.f, 0.f, 0.f, 0.f};
    float csum[2] = {0.f, 0.f};

    const int nkt = (q0 >> 6) + 1;
    for (int kt = sub; kt < nkt; kt += 2) {
        const int kv0 = kt * 64;
        const bool maskt = (kt == nkt - 1);

        // WAR guard: previous PV reads of this wave's P must be done
        asm volatile("s_waitcnt lgkmcnt(0)" ::: "memory");

        // ---- scores: S^T[kv][m] = K * Q^T ----
        #pragma unroll
        for (int mi = 0; mi < 4; ++mi) {
            const bf16* krow = Kh + (size_t)(kv0 + mi * 16 + l) * HD;
            bf16x8 ka0 = *(const bf16x8*)(krow + quad * 8);
            bf16x8 ka1 = *(const bf16x8*)(krow + 32 + quad * 8);
            #pragma unroll
            for (int ni = 0; ni < 2; ++ni) {
                f32x4 c = (f32x4){0.f, 0.f, 0.f, 0.f};
                c = MFMA(ka0, qf[ni][0], c);
                c = MFMA(ka1, qf[ni][1], c);
                const int kvb  = kv0 + mi * 16 + quad * 4;
                const int mcol = q0 + ni * 16 + l;
                bf16x4 pk;
                float lsum = 0.f;
                #pragma unroll
                for (int r = 0; r < 4; ++r) {
                    float p = __builtin_amdgcn_exp2f(c[r]);
                    if (maskt && (kvb + r > mcol)) p = 0.f;
                    lsum += p;
                    pk[r] = (bf16)p;
                }
                csum[ni] += lsum;
                *(bf16x4*)(Pw + (ni * 16 + l) * 72 + mi * 16 + quad * 4) = pk;
            }
        }

        // make this wave's P writes visible to its own cross-lane reads
        asm volatile("s_waitcnt lgkmcnt(0)" ::: "memory");

        // ---- PV: O[m][d] += P[m][kp] * Vt[d][kp]^T ----
        #pragma unroll
        for (int ks = 0; ks < 2; ++ks) {
            bf16x8 pa[2];
            #pragma unroll
            for (int mi = 0; mi < 2; ++mi)
                pa[mi] = *(const bf16x8*)(Pw + (mi * 16 + l) * 72 + ks * 32 + quad * 8);
            #pragma unroll
            for (int ni = 0; ni < 4; ++ni) {
                bf16x8 vb = *(const bf16x8*)(Vth + (size_t)(ni * 16 + l) * S_LEN + kv0 + ks * 32 + quad * 8);
                #pragma unroll
                for (int mi = 0; mi < 2; ++mi)
                    O[mi][ni] = MFMA(pa[mi], vb, O[mi][ni]);
            }
        }
    }

    // ---------------- epilogue: combine wave pairs ----------------
    __syncthreads();            // all P buffers dead; smem reusable
    float* Ob1  = (float*)smem;             // [32][64]  8 KB  (stream 1)
    float* Ob2  = (float*)(smem + 8192);    // [32][64]  8 KB  (stream 2)
    float* cbs1 = (float*)(smem + 16384);   // [2 waves][2 ni][64] 1 KB
    float* cbs2 = (float*)(smem + 17408);   // 1 KB

    float* cbs = (sid == 0) ? cbs1 : cbs2;
    cbs[sub * 128 + lane]      = csum[0];
    cbs[sub * 128 + 64 + lane] = csum[1];

    float* Ob = (sid == 0) ? Ob1 : Ob2;
    if (sub == 0) {
        #pragma unroll
        for (int mi = 0; mi < 2; ++mi)
            #pragma unroll
            for (int ni = 0; ni < 4; ++ni)
                #pragma unroll
                for (int r = 0; r < 4; ++r)
                    Ob[(mi * 16 + quad * 4 + r) * 64 + ni * 16 + l] = O[mi][ni][r];
    }
    __syncthreads();
    if (sub == 1) {
        #pragma unroll
        for (int mi = 0; mi < 2; ++mi)
            #pragma unroll
            for (int ni = 0; ni < 4; ++ni)
                #pragma unroll
                for (int r = 0; r < 4; ++r)
                    Ob[(mi * 16 + quad * 4 + r) * 64 + ni * 16 + l] += O[mi][ni][r];
    }
    __syncthreads();

    // per-thread final: row = tid>>3 (0..31), cols (tid&7)*8 .. +8
    const float lam = lam_p[0];
    const int row = tid >> 3;
    const int cb8 = (tid & 7) * 8;
    const int ni_r = row >> 4, l_r = row & 15;
    float den1 = 0.f, den2 = 0.f;
    #pragma unroll
    for (int w = 0; w < 2; ++w)
        #pragma unroll
        for (int q = 0; q < 4; ++q) {
            den1 += cbs1[w * 128 + ni_r * 64 + q * 16 + l_r];
            den2 += cbs2[w * 128 + ni_r * 64 + q * 16 + l_r];
        }
    const float inv1 = 1.0f / den1;
    const float inv2 = lam / den2;

    float v[8]; float ssq = 0.f;
    #pragma unroll
    for (int j = 0; j < 8; ++j) {
        const float x = Ob1[row * 64 + cb8 + j] * inv1 - Ob2[row * 64 + cb8 + j] * inv2;
        v[j] = x;
        ssq += x * x;
    }
    ssq += __shfl_xor(ssq, 1, 64);
    ssq += __shfl_xor(ssq, 2, 64);
    ssq += __shfl_xor(ssq, 4, 64);
    const float rms = rsqrtf(ssq * (1.0f / 64.0f) + RMS_EPS) * ONE_MINUS_LAM_INIT;

    bf16x8 ov;
    #pragma unroll
    for (int j = 0; j < 8; ++j)
        ov[j] = (bf16)(v[j] * rms * subln_w[cb8 + j]);
    *(bf16x8*)(attn_out + (size_t)(q0 + row) * HID_DIM + h * 64 + cb8) = ov;
}

// ---------------------------------------------------------------------------
// Workspace layout: see R1 (unchanged), total ~151 MB
// ---------------------------------------------------------------------------
extern "C" void kernel_launch(void* const* d_in, const int* in_sizes, int n_in,
                              void* d_out, int out_size, void* d_ws, size_t ws_size,
                              hipStream_t stream) {
    const float* hs  = (const float*)d_in[0];
    const float* Wq  = (const float*)d_in[1];
    const float* Wk  = (const float*)d_in[2];
    const float* Wv  = (const float*)d_in[3];
    const float* Wo  = (const float*)d_in[4];
    const float* lq1 = (const float*)d_in[5];
    const float* lk1 = (const float*)d_in[6];
    const float* lq2 = (const float*)d_in[7];
    const float* lk2 = (const float*)d_in[8];
    const float* slw = (const float*)d_in[9];

    if (ws_size < 151000000u) return;

    char* ws = (char*)d_ws;
    bf16*  hsb  = (bf16*)(ws);
    bf16*  Wb   = (bf16*)(ws + 8388608);
    bf16*  Wob  = (bf16*)(ws + 50331648);
    bf16*  qkv  = (bf16*)(ws + 58720256);
    bf16*  Q1b  = (bf16*)(ws + 100663296);
    bf16*  K1b  = (bf16*)(ws + 109051904);
    bf16*  Q2b  = (bf16*)(ws + 117440512);
    bf16*  K2b  = (bf16*)(ws + 125829120);
    bf16*  Vtb  = (bf16*)(ws + 134217728);
    bf16*  abuf = (bf16*)(ws + 142606336);
    float* lamp = (float*)(ws + 150994944);

    cvt_f32_bf16<<<4096, 256, 0, stream>>>(hs, hsb, 4194304);
    cvt_f32_bf16<<<8192, 256, 0, stream>>>(Wq, Wb, 8388608);
    cvt_f32_bf16<<<8192, 256, 0, stream>>>(Wk, Wb + 8388608, 8388608);
    cvt_f32_bf16<<<4096, 256, 0, stream>>>(Wv, Wb + 16777216, 4194304);
    cvt_f32_bf16<<<4096, 256, 0, stream>>>(Wo, Wob, 4194304);
    lam_kernel<<<1, 64, 0, stream>>>(lq1, lk1, lq2, lk2, lamp);

    gemm_bt<1><<<dim3(QKV_N / 128, S_LEN / 128), 256, 0, stream>>>(
        hsb, Wb, qkv, S_LEN, QKV_N, HID_DIM);

    rope_split<<<dim3(S_LEN / 64, NHEAD), 256, 0, stream>>>(qkv, Q1b, K1b, Q2b, K2b, Vtb);

    diff_attn<<<dim3(S_LEN / 32, NHEAD), 256, 0, stream>>>(
        Q1b, K1b, Q2b, K2b, Vtb, lamp, slw, abuf);

    gemm_bt<0><<<dim3(HID_DIM / 128, S_LEN / 128), 256, 0, stream>>>(
        abuf, Wob, d_out, S_LEN, HID_DIM, HID_DIM);
}

// Round 4
// 405.111 us; speedup vs baseline: 1.4657x; 1.3570x over previous
//
#include <hip/hip_runtime.h>

// ---------------------------------------------------------------------------
// LlamaDifferentialAttentionBase on MI355X (gfx950)
// B=1, S=2048, HID=2048, H=32, D=64. All inputs fp32; output fp32.
// R4: diff_attn -> block-cooperative flash: 4 waves = 2 streams x 2 q-halves
//     over a 128-row q-tile; K1/K2/Vt staged to LDS per kv-tile via
//     global_load_lds (swizzled), m97 2-barrier loop; 64 MFMA/wave/tile.
// ---------------------------------------------------------------------------

typedef __bf16 bf16;
typedef __bf16 bf16x4 __attribute__((ext_vector_type(4)));
typedef __bf16 bf16x8 __attribute__((ext_vector_type(8)));
typedef float  f32x4  __attribute__((ext_vector_type(4)));

#define MFMA(a, b, c) __builtin_amdgcn_mfma_f32_16x16x32_bf16((a), (b), (c), 0, 0, 0)

#define S_LEN   2048
#define HID_DIM 2048
#define NHEAD   32
#define HD      64
#define QKV_N   10240                 // 4096 (q) + 4096 (k) + 2048 (v)
#define LAM_INIT 0.7836057665316245f  // 0.8 - 0.6*exp(-0.3*12)
#define ONE_MINUS_LAM_INIT 0.21639423346837553f
#define QSCALE  0.18033688011112042f  // (1/sqrt(64)) * log2(e)
#define RMS_EPS 1e-6f

// async global->LDS, 16B per lane; LDS dest = wave-uniform base + lane*16
__device__ __forceinline__ void gld16(const void* g, void* l) {
    __builtin_amdgcn_global_load_lds(
        (const __attribute__((address_space(1))) void*)g,
        (__attribute__((address_space(3))) void*)l, 16, 0, 0);
}

// ---------------------------------------------------------------------------
// fp32 -> bf16, float4-vectorized
// ---------------------------------------------------------------------------
__global__ void cvt_f32_bf16(const float* __restrict__ src, bf16* __restrict__ dst, int n) {
    int i = (blockIdx.x * 256 + threadIdx.x) * 4;
    if (i + 3 < n) {
        float4 v = *(const float4*)(src + i);
        bf16x4 o = { (bf16)v.x, (bf16)v.y, (bf16)v.z, (bf16)v.w };
        *(bf16x4*)(dst + i) = o;
    }
}

// ---------------------------------------------------------------------------
// lambda scalar
// ---------------------------------------------------------------------------
__global__ void lam_kernel(const float* __restrict__ lq1, const float* __restrict__ lk1,
                           const float* __restrict__ lq2, const float* __restrict__ lk2,
                           float* __restrict__ out) {
    int t = threadIdx.x;
    float a = lq1[t] * lk1[t];
    float b = lq2[t] * lk2[t];
    #pragma unroll
    for (int off = 32; off > 0; off >>= 1) {
        a += __shfl_xor(a, off, 64);
        b += __shfl_xor(b, off, 64);
    }
    if (t == 0) out[0] = expf(a) - expf(b) + LAM_INIT;
}

// ---------------------------------------------------------------------------
// GEMM: C[M,N] = A[M,K] * B[N,K]^T, 128x128 tile, BK=32, 4 waves,
// m97-style global_load_lds staging (unchanged from R3).
// ---------------------------------------------------------------------------
template<int OUT_BF16>
__global__ __launch_bounds__(256, 2)
void gemm_bt(const bf16* __restrict__ A, const bf16* __restrict__ B,
             void* __restrict__ Cout, int M, int N, int K) {
    __shared__ __align__(16) bf16 As[128 * 32];
    __shared__ __align__(16) bf16 Bs[128 * 32];
    const int tid  = threadIdx.x;
    const int wave = tid >> 6, lane = tid & 63;
    const int wm = wave >> 1, wn = wave & 1;
    const int l = lane & 15, quad = lane >> 4;
    const int m0 = blockIdx.y * 128, n0 = blockIdx.x * 128;

    f32x4 acc[4][4];
    #pragma unroll
    for (int i = 0; i < 4; ++i)
        #pragma unroll
        for (int j = 0; j < 4; ++j) acc[i][j] = (f32x4){0.f, 0.f, 0.f, 0.f};

    const int r0 = tid >> 2, c0 = (tid & 3) * 8;
    const bf16* Ag = A + (size_t)(m0 + r0) * K + c0;
    const bf16* Bg = B + (size_t)(n0 + r0) * K + c0;
    bf16* As0 = As + tid * 8;
    bf16* Bs0 = Bs + tid * 8;

    for (int kt = 0; kt < K; kt += 32) {
        __syncthreads();
        gld16(Ag + kt, As0);
        gld16(Ag + (size_t)64 * K + kt, As0 + 2048);
        gld16(Bg + kt, Bs0);
        gld16(Bg + (size_t)64 * K + kt, Bs0 + 2048);
        __syncthreads();

        bf16x8 af[4], bfr[4];
        #pragma unroll
        for (int mi = 0; mi < 4; ++mi)
            af[mi] = *(const bf16x8*)(As + (wm * 64 + mi * 16 + l) * 32 + quad * 8);
        #pragma unroll
        for (int ni = 0; ni < 4; ++ni)
            bfr[ni] = *(const bf16x8*)(Bs + (wn * 64 + ni * 16 + l) * 32 + quad * 8);
        #pragma unroll
        for (int mi = 0; mi < 4; ++mi)
            #pragma unroll
            for (int ni = 0; ni < 4; ++ni)
                acc[mi][ni] = MFMA(af[mi], bfr[ni], acc[mi][ni]);
    }

    #pragma unroll
    for (int mi = 0; mi < 4; ++mi)
        #pragma unroll
        for (int ni = 0; ni < 4; ++ni)
            #pragma unroll
            for (int r = 0; r < 4; ++r) {
                const int row = m0 + wm * 64 + mi * 16 + quad * 4 + r;
                const int col = n0 + wn * 64 + ni * 16 + l;
                const float v = acc[mi][ni][r];
                if (OUT_BF16) ((bf16*)Cout)[(size_t)row * N + col] = (bf16)v;
                else          ((float*)Cout)[(size_t)row * N + col] = v;
            }
}

// ---------------------------------------------------------------------------
// RoPE + head split (unchanged)
// ---------------------------------------------------------------------------
__global__ __launch_bounds__(256)
void rope_split(const bf16* __restrict__ qkv,
                bf16* __restrict__ Q1, bf16* __restrict__ K1,
                bf16* __restrict__ Q2, bf16* __restrict__ K2,
                bf16* __restrict__ Vt) {
    const int h = blockIdx.y;
    const int s0 = blockIdx.x * 64;
    const int t = threadIdx.x;
    const int d = t & 63, sr = t >> 6;
    __shared__ __align__(16) bf16 vt_lds[64][72];

    const int i = d & 31;
    const float invf = exp2f(-(float)i * 0.4152410118609203f);
    const float sign = (d < 32) ? -1.0f : 1.0f;

    for (int it = 0; it < 16; ++it) {
        const int s = s0 + it * 4 + sr;
        const bf16* row = qkv + (size_t)s * QKV_N;
        const int cb  = h * 64 + d;
        const int cbo = h * 64 + (d ^ 32);
        const float ang = (float)s * invf;
        const float cs = cosf(ang), sn = sinf(ang);
        const float q1v = (float)row[cb],         q1o = (float)row[cbo];
        const float q2v = (float)row[2048 + cb],  q2o = (float)row[2048 + cbo];
        const float k1v = (float)row[4096 + cb],  k1o = (float)row[4096 + cbo];
        const float k2v = (float)row[6144 + cb],  k2o = (float)row[6144 + cbo];
        const float vv  = (float)row[8192 + cb];
        const size_t o = ((size_t)h * S_LEN + s) * HD + d;
        Q1[o] = (bf16)((q1v * cs + sign * q1o * sn) * QSCALE);
        Q2[o] = (bf16)((q2v * cs + sign * q2o * sn) * QSCALE);
        K1[o] = (bf16)(k1v * cs + sign * k1o * sn);
        K2[o] = (bf16)(k2v * cs + sign * k2o * sn);
        vt_lds[d][it * 4 + sr] = (bf16)vv;
    }
    __syncthreads();
    const int dd = t >> 2, cg = t & 3;
    bf16x8 w0 = *(const bf16x8*)(&vt_lds[dd][cg * 16]);
    bf16x8 w1 = *(const bf16x8*)(&vt_lds[dd][cg * 16 + 8]);
    bf16* dst = Vt + ((size_t)h * HD + dd) * S_LEN + s0 + cg * 16;
    *(bf16x8*)(dst)     = w0;
    *(bf16x8*)(dst + 8) = w1;
}

// ---------------------------------------------------------------------------
// Differential flash attention, R4:
//  - 1 block = 4 waves = (stream, q-half): w0=s1/rows0-63, w1=s1/rows64-127,
//    w2=s2/rows0-63, w3=s2/rows64-127. Block q-tile = 128 rows of one head.
//  - Per kv tile (64): stage K1,K2,Vt (24 KB) to LDS with global_load_lds,
//    XOR-swizzled 16B chunks so b128 fragment reads are ~2-way conflict max.
//  - Each wave: QK^T (32 MFMA) from LDS K + reg Q -> exp2/mask -> P (LDS,
//    wave-private) -> PV (32 MFMA) with LDS Vt. 64 MFMA / wave / tile.
//  - Epilogue: stream-2 waves write lam/den2-scaled O2 to LDS; stream-1
//    waves combine, RMSNorm, store bf16.
//  - Grid 512: bid pairs heavy/light qb: even->qb 15-i, odd->qb i.
// ---------------------------------------------------------------------------
__global__ __launch_bounds__(256, 2)
void diff_attn(const bf16* __restrict__ Q1, const bf16* __restrict__ K1,
               const bf16* __restrict__ Q2, const bf16* __restrict__ K2,
               const bf16* __restrict__ Vt, const float* __restrict__ lam_p,
               const float* __restrict__ subln_w, bf16* __restrict__ attn_out) {
    const int bid  = blockIdx.x;
    const int h    = (bid >> 1) & 31;
    const int idx  = bid >> 6;                       // 0..7
    const int qb   = (bid & 1) ? idx : (15 - idx);   // heavy/light pairing
    const int q0   = qb * 128;
    const int tid  = threadIdx.x;
    const int wave = tid >> 6, lane = tid & 63;
    const int sid  = wave >> 1, half = wave & 1;
    const int l    = lane & 15, quad = lane >> 4;
    const int q0w  = q0 + half * 64;

    __shared__ __align__(16) char smem[61440];
    bf16* K1s = (bf16*)smem;                       // [64][64] swizzled, 8 KB
    bf16* K2s = (bf16*)(smem + 8192);
    bf16* Vts = (bf16*)(smem + 16384);
    bf16* Pw  = (bf16*)(smem + 24576 + wave * 9216); // [64][72] wave-private

    const bf16* Qh  = (sid ? Q2 : Q1) + ((size_t)h * S_LEN + q0w) * HD;
    const bf16* K1g = K1 + (size_t)h * S_LEN * HD;
    const bf16* K2g = K2 + (size_t)h * S_LEN * HD;
    const bf16* Vtg = Vt + (size_t)h * HD * S_LEN;
    const bf16* Ksm = sid ? K2s : K1s;

    // staging geometry: row rr (0..31, +32 round 2), swizzled chunk
    const int rr  = tid >> 3;
    const int csw = ((tid & 7) ^ (rr & 7)) * 8;    // elem offset of 16B chunk
    bf16* l1 = K1s + tid * 8;
    bf16* l2 = K2s + tid * 8;
    bf16* lv = Vts + tid * 8;

    // Q fragments (B-operand): B[n = ni*16+l][k = ks*32+quad*8..]
    bf16x8 qf[4][2];
    #pragma unroll
    for (int ni = 0; ni < 4; ++ni)
        #pragma unroll
        for (int ks = 0; ks < 2; ++ks)
            qf[ni][ks] = *(const bf16x8*)(Qh + (ni * 16 + l) * HD + ks * 32 + quad * 8);

    f32x4 O[4][4];
    #pragma unroll
    for (int mi = 0; mi < 4; ++mi)
        #pragma unroll
        for (int ni = 0; ni < 4; ++ni)
            O[mi][ni] = (f32x4){0.f, 0.f, 0.f, 0.f};
    float csum[4] = {0.f, 0.f, 0.f, 0.f};

    const int T = 2 * qb + 2;
    const int sw8 = l & 7;
    for (int t = 0; t < T; ++t) {
        const int kv0 = t * 64;
        __syncthreads();                           // LDS consumers of tile t-1 done
        {   // stage K1, K2, Vt tiles (24 KB)
            const bf16* k1p = K1g + (size_t)(kv0 + rr) * HD + csw;
            const bf16* k2p = K2g + (size_t)(kv0 + rr) * HD + csw;
            const bf16* vtp = Vtg + (size_t)rr * S_LEN + kv0 + csw;
            gld16(k1p, l1);
            gld16(k1p + (size_t)32 * HD, l1 + 2048);
            gld16(k2p, l2);
            gld16(k2p + (size_t)32 * HD, l2 + 2048);
            gld16(vtp, lv);
            gld16(vtp + (size_t)32 * S_LEN, lv + 2048);
        }
        __syncthreads();                           // drains vmcnt

        if (kv0 <= q0w) {                          // wave-uniform
            const bool diag = (kv0 == q0w);

            // ---- QK^T -> S^T[kv][q], exp2, P write ----
            #pragma unroll
            for (int mi = 0; mi < 4; ++mi) {
                const int krow = (mi * 16 + l) * 64;
                bf16x8 ka0 = *(const bf16x8*)(Ksm + krow + ((quad ^ sw8) << 3));
                bf16x8 ka1 = *(const bf16x8*)(Ksm + krow + (((4 + quad) ^ sw8) << 3));
                #pragma unroll
                for (int ni = 0; ni < 4; ++ni) {
                    f32x4 c = (f32x4){0.f, 0.f, 0.f, 0.f};
                    c = MFMA(ka0, qf[ni][0], c);
                    c = MFMA(ka1, qf[ni][1], c);
                    bf16x4 pk;
                    float lsum = 0.f;
                    #pragma unroll
                    for (int r = 0; r < 4; ++r) {
                        float p = __builtin_amdgcn_exp2f(c[r]);
                        if (diag && (mi * 16 + quad * 4 + r > ni * 16 + l)) p = 0.f;
                        lsum += p;
                        pk[r] = (bf16)p;
                    }
                    csum[ni] += lsum;
                    *(bf16x4*)(Pw + (ni * 16 + l) * 72 + mi * 16 + quad * 4) = pk;
                }
            }

            // Vt fragments can load while P writes drain (disjoint LDS)
            bf16x8 vb[2][4];
            #pragma unroll
            for (int ks = 0; ks < 2; ++ks)
                #pragma unroll
                for (int ni = 0; ni < 4; ++ni)
                    vb[ks][ni] = *(const bf16x8*)(Vts + (ni * 16 + l) * 64 +
                                                  ((((ks << 2) + quad) ^ sw8) << 3));

            // cross-lane P RAW: drain DS queue (in-order per wave)
            asm volatile("s_waitcnt lgkmcnt(0)" ::: "memory");

            // ---- PV: O[q][d] += P[q][kv] * Vt[d][kv]^T ----
            #pragma unroll
            for (int ks = 0; ks < 2; ++ks) {
                bf16x8 pa[4];
                #pragma unroll
                for (int mi = 0; mi < 4; ++mi)
                    pa[mi] = *(const bf16x8*)(Pw + (mi * 16 + l) * 72 + ks * 32 + quad * 8);
                #pragma unroll
                for (int ni = 0; ni < 4; ++ni)
                    #pragma unroll
                    for (int mi = 0; mi < 4; ++mi)
                        O[mi][ni] = MFMA(pa[mi], vb[ks][ni], O[mi][ni]);
            }
        }
    }

    // ---------------- epilogue ----------------
    __syncthreads();                               // all tile LDS dead
    float* epi = (float*)(smem + half * 16640);    // [64][65] f32 per q-half

    // full denominators: reduce across quads; lane l then holds den[q=ni*16+l]
    #pragma unroll
    for (int ni = 0; ni < 4; ++ni) {
        csum[ni] += __shfl_xor(csum[ni], 16, 64);
        csum[ni] += __shfl_xor(csum[ni], 32, 64);
    }

    if (sid == 1) {
        const float lam = lam_p[0];
        #pragma unroll
        for (int mi = 0; mi < 4; ++mi)
            #pragma unroll
            for (int r = 0; r < 4; ++r) {
                const float inv = lam / __shfl(csum[mi], quad * 4 + r, 64);
                const int row = mi * 16 + quad * 4 + r;
                #pragma unroll
                for (int ni = 0; ni < 4; ++ni)
                    epi[row * 65 + ni * 16 + l] = O[mi][ni][r] * inv;
            }
    }
    __syncthreads();

    if (sid == 0) {
        float sw[4];
        #pragma unroll
        for (int ni = 0; ni < 4; ++ni) sw[ni] = subln_w[ni * 16 + l];

        #pragma unroll
        for (int mi = 0; mi < 4; ++mi) {
            float inv1[4];
            #pragma unroll
            for (int r = 0; r < 4; ++r)
                inv1[r] = 1.0f / __shfl(csum[mi], quad * 4 + r, 64);

            float v[4][4]; float ssq[4] = {0.f, 0.f, 0.f, 0.f};
            #pragma unroll
            for (int ni = 0; ni < 4; ++ni)
                #pragma unroll
                for (int r = 0; r < 4; ++r) {
                    const int row = mi * 16 + quad * 4 + r;
                    const float x = O[mi][ni][r] * inv1[r] - epi[row * 65 + ni * 16 + l];
                    v[ni][r] = x;
                    ssq[r] += x * x;
                }
            #pragma unroll
            for (int r = 0; r < 4; ++r) {
                float s = ssq[r];
                s += __shfl_xor(s, 1, 64);
                s += __shfl_xor(s, 2, 64);
                s += __shfl_xor(s, 4, 64);
                s += __shfl_xor(s, 8, 64);
                ssq[r] = rsqrtf(s * (1.0f / 64.0f) + RMS_EPS) * ONE_MINUS_LAM_INIT;
            }
            #pragma unroll
            for (int ni = 0; ni < 4; ++ni)
                #pragma unroll
                for (int r = 0; r < 4; ++r) {
                    const int row = q0w + mi * 16 + quad * 4 + r;
                    attn_out[(size_t)row * HID_DIM + h * 64 + ni * 16 + l] =
                        (bf16)(v[ni][r] * ssq[r] * sw[ni]);
                }
        }
    }
}

// ---------------------------------------------------------------------------
// Workspace layout: see R1 (unchanged), total ~151 MB
// ---------------------------------------------------------------------------
extern "C" void kernel_launch(void* const* d_in, const int* in_sizes, int n_in,
                              void* d_out, int out_size, void* d_ws, size_t ws_size,
                              hipStream_t stream) {
    const float* hs  = (const float*)d_in[0];
    const float* Wq  = (const float*)d_in[1];
    const float* Wk  = (const float*)d_in[2];
    const float* Wv  = (const float*)d_in[3];
    const float* Wo  = (const float*)d_in[4];
    const float* lq1 = (const float*)d_in[5];
    const float* lk1 = (const float*)d_in[6];
    const float* lq2 = (const float*)d_in[7];
    const float* lk2 = (const float*)d_in[8];
    const float* slw = (const float*)d_in[9];

    if (ws_size < 151000000u) return;

    char* ws = (char*)d_ws;
    bf16*  hsb  = (bf16*)(ws);
    bf16*  Wb   = (bf16*)(ws + 8388608);
    bf16*  Wob  = (bf16*)(ws + 50331648);
    bf16*  qkv  = (bf16*)(ws + 58720256);
    bf16*  Q1b  = (bf16*)(ws + 100663296);
    bf16*  K1b  = (bf16*)(ws + 109051904);
    bf16*  Q2b  = (bf16*)(ws + 117440512);
    bf16*  K2b  = (bf16*)(ws + 125829120);
    bf16*  Vtb  = (bf16*)(ws + 134217728);
    bf16*  abuf = (bf16*)(ws + 142606336);
    float* lamp = (float*)(ws + 150994944);

    cvt_f32_bf16<<<4096, 256, 0, stream>>>(hs, hsb, 4194304);
    cvt_f32_bf16<<<8192, 256, 0, stream>>>(Wq, Wb, 8388608);
    cvt_f32_bf16<<<8192, 256, 0, stream>>>(Wk, Wb + 8388608, 8388608);
    cvt_f32_bf16<<<4096, 256, 0, stream>>>(Wv, Wb + 16777216, 4194304);
    cvt_f32_bf16<<<4096, 256, 0, stream>>>(Wo, Wob, 4194304);
    lam_kernel<<<1, 64, 0, stream>>>(lq1, lk1, lq2, lk2, lamp);

    gemm_bt<1><<<dim3(QKV_N / 128, S_LEN / 128), 256, 0, stream>>>(
        hsb, Wb, qkv, S_LEN, QKV_N, HID_DIM);

    rope_split<<<dim3(S_LEN / 64, NHEAD), 256, 0, stream>>>(qkv, Q1b, K1b, Q2b, K2b, Vtb);

    diff_attn<<<512, 256, 0, stream>>>(Q1b, K1b, Q2b, K2b, Vtb, lamp, slw, abuf);

    gemm_bt<0><<<dim3(HID_DIM / 128, S_LEN / 128), 256, 0, stream>>>(
        abuf, Wob, d_out, S_LEN, HID_DIM, HID_DIM);
}

// Round 5
// 369.379 us; speedup vs baseline: 1.6074x; 1.0967x over previous
//
#include <hip/hip_runtime.h>

// ---------------------------------------------------------------------------
// LlamaDifferentialAttentionBase on MI355X (gfx950)
// B=1, S=2048, HID=2048, H=32, D=64. All inputs fp32; output fp32.
// R5: gemm -> BK=64 + XOR-swizzled LDS (conflict-free b128 fragment reads,
//     half the barriers); O-proj -> split-K=2 (+reduce); cvt+lam fused into
//     one kernel. diff_attn/rope unchanged from R4.
// ---------------------------------------------------------------------------

typedef __bf16 bf16;
typedef __bf16 bf16x4 __attribute__((ext_vector_type(4)));
typedef __bf16 bf16x8 __attribute__((ext_vector_type(8)));
typedef float  f32x4  __attribute__((ext_vector_type(4)));

#define MFMA(a, b, c) __builtin_amdgcn_mfma_f32_16x16x32_bf16((a), (b), (c), 0, 0, 0)

#define S_LEN   2048
#define HID_DIM 2048
#define NHEAD   32
#define HD      64
#define QKV_N   10240                 // 4096 (q) + 4096 (k) + 2048 (v)
#define LAM_INIT 0.7836057665316245f  // 0.8 - 0.6*exp(-0.3*12)
#define ONE_MINUS_LAM_INIT 0.21639423346837553f
#define QSCALE  0.18033688011112042f  // (1/sqrt(64)) * log2(e)
#define RMS_EPS 1e-6f

// async global->LDS, 16B per lane; LDS dest = wave-uniform base + lane*16
__device__ __forceinline__ void gld16(const void* g, void* l) {
    __builtin_amdgcn_global_load_lds(
        (const __attribute__((address_space(1))) void*)g,
        (__attribute__((address_space(3))) void*)l, 16, 0, 0);
}

// ---------------------------------------------------------------------------
// Fused fp32->bf16 for all 5 tensors + lambda scalar (last block).
// Block ranges (1024 elems each): hs 4096 | Wq 8192 | Wk 8192 | Wv 4096 | Wo 4096
// ---------------------------------------------------------------------------
__global__ void cvt_all(const float* __restrict__ hs, const float* __restrict__ Wq,
                        const float* __restrict__ Wk, const float* __restrict__ Wv,
                        const float* __restrict__ Wo,
                        const float* __restrict__ lq1, const float* __restrict__ lk1,
                        const float* __restrict__ lq2, const float* __restrict__ lk2,
                        bf16* __restrict__ hsb, bf16* __restrict__ Wb,
                        bf16* __restrict__ Wob, float* __restrict__ lam_out) {
    const int bid = blockIdx.x;
    if (bid >= 28672) {               // lambda block
        const int t = threadIdx.x;
        if (t < 64) {
            float a = lq1[t] * lk1[t];
            float b = lq2[t] * lk2[t];
            #pragma unroll
            for (int off = 32; off > 0; off >>= 1) {
                a += __shfl_xor(a, off, 64);
                b += __shfl_xor(b, off, 64);
            }
            if (t == 0) lam_out[0] = expf(a) - expf(b) + LAM_INIT;
        }
        return;
    }
    const float* src; bf16* dst; int off;
    if      (bid <  4096) { src = hs; dst = hsb;            off = bid;         }
    else if (bid < 12288) { src = Wq; dst = Wb;             off = bid - 4096;  }
    else if (bid < 20480) { src = Wk; dst = Wb +  8388608;  off = bid - 12288; }
    else if (bid < 24576) { src = Wv; dst = Wb + 16777216;  off = bid - 20480; }
    else                  { src = Wo; dst = Wob;            off = bid - 24576; }
    const int i = off * 1024 + threadIdx.x * 4;
    float4 v = *(const float4*)(src + i);
    bf16x4 o = { (bf16)v.x, (bf16)v.y, (bf16)v.z, (bf16)v.w };
    *(bf16x4*)(dst + i) = o;
}

// ---------------------------------------------------------------------------
// GEMM: C[M,N] = A[M,K] * B[N,K]^T  (row-major bf16, B^T layout)
// 128x128 tile, BK=64, 4 waves, global_load_lds staging with XOR swizzle:
// chunk c (16B) of row r stored at position c^(r&7) -> ds_read_b128 fragment
// reads are conflict-free (8-lane phase covers all 32 banks).
// OUT_MODE: 0 = f32, 1 = bf16, 2 = f32 partial at Cout + z*M*N (split-K).
// ---------------------------------------------------------------------------
template<int OUT_MODE>
__global__ __launch_bounds__(256, 3)
void gemm_bt(const bf16* __restrict__ A, const bf16* __restrict__ B,
             void* __restrict__ Cout, int M, int N, int K_total, int K_part) {
    __shared__ __align__(16) bf16 As[128 * 64];
    __shared__ __align__(16) bf16 Bs[128 * 64];
    const int tid  = threadIdx.x;
    const int wave = tid >> 6, lane = tid & 63;
    const int wm = wave >> 1, wn = wave & 1;
    const int l = lane & 15, quad = lane >> 4;
    const int m0 = blockIdx.y * 128, n0 = blockIdx.x * 128;
    const int kz = blockIdx.z * K_part;

    f32x4 acc[4][4];
    #pragma unroll
    for (int i = 0; i < 4; ++i)
        #pragma unroll
        for (int j = 0; j < 4; ++j) acc[i][j] = (f32x4){0.f, 0.f, 0.f, 0.f};

    // staging: thread -> row rr (+32j), swizzled 16B chunk
    const int rr  = tid >> 3;
    const int csw = ((tid & 7) ^ (rr & 7)) * 8;
    const bf16* Ag = A + (size_t)(m0 + rr) * K_total + kz + csw;
    const bf16* Bg = B + (size_t)(n0 + rr) * K_total + kz + csw;

    for (int kt = 0; kt < K_part; kt += 64) {
        __syncthreads();
        #pragma unroll
        for (int j = 0; j < 4; ++j) {
            gld16(Ag + (size_t)(32 * j) * K_total + kt, As + j * 2048 + tid * 8);
            gld16(Bg + (size_t)(32 * j) * K_total + kt, Bs + j * 2048 + tid * 8);
        }
        __syncthreads();   // drains vmcnt before barrier

        #pragma unroll
        for (int ks = 0; ks < 2; ++ks) {
            const int co = (((ks << 2) | quad) ^ (l & 7)) << 3;
            bf16x8 af[4], bfr[4];
            #pragma unroll
            for (int mi = 0; mi < 4; ++mi)
                af[mi] = *(const bf16x8*)(As + (wm * 64 + mi * 16 + l) * 64 + co);
            #pragma unroll
            for (int ni = 0; ni < 4; ++ni)
                bfr[ni] = *(const bf16x8*)(Bs + (wn * 64 + ni * 16 + l) * 64 + co);
            #pragma unroll
            for (int mi = 0; mi < 4; ++mi)
                #pragma unroll
                for (int ni = 0; ni < 4; ++ni)
                    acc[mi][ni] = MFMA(af[mi], bfr[ni], acc[mi][ni]);
        }
    }

    // C/D layout: row = quad*4 + r, col = lane&15
    float* Pf = (OUT_MODE == 2)
              ? ((float*)Cout + (size_t)blockIdx.z * M * N) : (float*)Cout;
    #pragma unroll
    for (int mi = 0; mi < 4; ++mi)
        #pragma unroll
        for (int ni = 0; ni < 4; ++ni)
            #pragma unroll
            for (int r = 0; r < 4; ++r) {
                const int row = m0 + wm * 64 + mi * 16 + quad * 4 + r;
                const int col = n0 + wn * 64 + ni * 16 + l;
                const float v = acc[mi][ni][r];
                if (OUT_MODE == 1) ((bf16*)Cout)[(size_t)row * N + col] = (bf16)v;
                else               Pf[(size_t)row * N + col] = v;
            }
}

// split-K reduce: out[i] = p[i] + p[n+i]  (fp32, float4)
__global__ void reduce_add(const float* __restrict__ p, float* __restrict__ out, int n) {
    const int i = (blockIdx.x * 256 + threadIdx.x) * 4;
    float4 a = *(const float4*)(p + i);
    float4 b = *(const float4*)(p + n + i);
    float4 o = { a.x + b.x, a.y + b.y, a.z + b.z, a.w + b.w };
    *(float4*)(out + i) = o;
}

// ---------------------------------------------------------------------------
// RoPE + head split (unchanged)
// ---------------------------------------------------------------------------
__global__ __launch_bounds__(256)
void rope_split(const bf16* __restrict__ qkv,
                bf16* __restrict__ Q1, bf16* __restrict__ K1,
                bf16* __restrict__ Q2, bf16* __restrict__ K2,
                bf16* __restrict__ Vt) {
    const int h = blockIdx.y;
    const int s0 = blockIdx.x * 64;
    const int t = threadIdx.x;
    const int d = t & 63, sr = t >> 6;
    __shared__ __align__(16) bf16 vt_lds[64][72];

    const int i = d & 31;
    const float invf = exp2f(-(float)i * 0.4152410118609203f);
    const float sign = (d < 32) ? -1.0f : 1.0f;

    for (int it = 0; it < 16; ++it) {
        const int s = s0 + it * 4 + sr;
        const bf16* row = qkv + (size_t)s * QKV_N;
        const int cb  = h * 64 + d;
        const int cbo = h * 64 + (d ^ 32);
        const float ang = (float)s * invf;
        const float cs = cosf(ang), sn = sinf(ang);
        const float q1v = (float)row[cb],         q1o = (float)row[cbo];
        const float q2v = (float)row[2048 + cb],  q2o = (float)row[2048 + cbo];
        const float k1v = (float)row[4096 + cb],  k1o = (float)row[4096 + cbo];
        const float k2v = (float)row[6144 + cb],  k2o = (float)row[6144 + cbo];
        const float vv  = (float)row[8192 + cb];
        const size_t o = ((size_t)h * S_LEN + s) * HD + d;
        Q1[o] = (bf16)((q1v * cs + sign * q1o * sn) * QSCALE);
        Q2[o] = (bf16)((q2v * cs + sign * q2o * sn) * QSCALE);
        K1[o] = (bf16)(k1v * cs + sign * k1o * sn);
        K2[o] = (bf16)(k2v * cs + sign * k2o * sn);
        vt_lds[d][it * 4 + sr] = (bf16)vv;
    }
    __syncthreads();
    const int dd = t >> 2, cg = t & 3;
    bf16x8 w0 = *(const bf16x8*)(&vt_lds[dd][cg * 16]);
    bf16x8 w1 = *(const bf16x8*)(&vt_lds[dd][cg * 16 + 8]);
    bf16* dst = Vt + ((size_t)h * HD + dd) * S_LEN + s0 + cg * 16;
    *(bf16x8*)(dst)     = w0;
    *(bf16x8*)(dst + 8) = w1;
}

// ---------------------------------------------------------------------------
// Differential flash attention (unchanged from R4)
// ---------------------------------------------------------------------------
__global__ __launch_bounds__(256, 2)
void diff_attn(const bf16* __restrict__ Q1, const bf16* __restrict__ K1,
               const bf16* __restrict__ Q2, const bf16* __restrict__ K2,
               const bf16* __restrict__ Vt, const float* __restrict__ lam_p,
               const float* __restrict__ subln_w, bf16* __restrict__ attn_out) {
    const int bid  = blockIdx.x;
    const int h    = (bid >> 1) & 31;
    const int idx  = bid >> 6;                       // 0..7
    const int qb   = (bid & 1) ? idx : (15 - idx);   // heavy/light pairing
    const int q0   = qb * 128;
    const int tid  = threadIdx.x;
    const int wave = tid >> 6, lane = tid & 63;
    const int sid  = wave >> 1, half = wave & 1;
    const int l    = lane & 15, quad = lane >> 4;
    const int q0w  = q0 + half * 64;

    __shared__ __align__(16) char smem[61440];
    bf16* K1s = (bf16*)smem;                       // [64][64] swizzled, 8 KB
    bf16* K2s = (bf16*)(smem + 8192);
    bf16* Vts = (bf16*)(smem + 16384);
    bf16* Pw  = (bf16*)(smem + 24576 + wave * 9216); // [64][72] wave-private

    const bf16* Qh  = (sid ? Q2 : Q1) + ((size_t)h * S_LEN + q0w) * HD;
    const bf16* K1g = K1 + (size_t)h * S_LEN * HD;
    const bf16* K2g = K2 + (size_t)h * S_LEN * HD;
    const bf16* Vtg = Vt + (size_t)h * HD * S_LEN;
    const bf16* Ksm = sid ? K2s : K1s;

    const int rr  = tid >> 3;
    const int csw = ((tid & 7) ^ (rr & 7)) * 8;    // elem offset of 16B chunk
    bf16* l1 = K1s + tid * 8;
    bf16* l2 = K2s + tid * 8;
    bf16* lv = Vts + tid * 8;

    bf16x8 qf[4][2];
    #pragma unroll
    for (int ni = 0; ni < 4; ++ni)
        #pragma unroll
        for (int ks = 0; ks < 2; ++ks)
            qf[ni][ks] = *(const bf16x8*)(Qh + (ni * 16 + l) * HD + ks * 32 + quad * 8);

    f32x4 O[4][4];
    #pragma unroll
    for (int mi = 0; mi < 4; ++mi)
        #pragma unroll
        for (int ni = 0; ni < 4; ++ni)
            O[mi][ni] = (f32x4){0.f, 0.f, 0.f, 0.f};
    float csum[4] = {0.f, 0.f, 0.f, 0.f};

    const int T = 2 * qb + 2;
    const int sw8 = l & 7;
    for (int t = 0; t < T; ++t) {
        const int kv0 = t * 64;
        __syncthreads();
        {
            const bf16* k1p = K1g + (size_t)(kv0 + rr) * HD + csw;
            const bf16* k2p = K2g + (size_t)(kv0 + rr) * HD + csw;
            const bf16* vtp = Vtg + (size_t)rr * S_LEN + kv0 + csw;
            gld16(k1p, l1);
            gld16(k1p + (size_t)32 * HD, l1 + 2048);
            gld16(k2p, l2);
            gld16(k2p + (size_t)32 * HD, l2 + 2048);
            gld16(vtp, lv);
            gld16(vtp + (size_t)32 * S_LEN, lv + 2048);
        }
        __syncthreads();

        if (kv0 <= q0w) {
            const bool diag = (kv0 == q0w);

            #pragma unroll
            for (int mi = 0; mi < 4; ++mi) {
                const int krow = (mi * 16 + l) * 64;
                bf16x8 ka0 = *(const bf16x8*)(Ksm + krow + ((quad ^ sw8) << 3));
                bf16x8 ka1 = *(const bf16x8*)(Ksm + krow + (((4 + quad) ^ sw8) << 3));
                #pragma unroll
                for (int ni = 0; ni < 4; ++ni) {
                    f32x4 c = (f32x4){0.f, 0.f, 0.f, 0.f};
                    c = MFMA(ka0, qf[ni][0], c);
                    c = MFMA(ka1, qf[ni][1], c);
                    bf16x4 pk;
                    float lsum = 0.f;
                    #pragma unroll
                    for (int r = 0; r < 4; ++r) {
                        float p = __builtin_amdgcn_exp2f(c[r]);
                        if (diag && (mi * 16 + quad * 4 + r > ni * 16 + l)) p = 0.f;
                        lsum += p;
                        pk[r] = (bf16)p;
                    }
                    csum[ni] += lsum;
                    *(bf16x4*)(Pw + (ni * 16 + l) * 72 + mi * 16 + quad * 4) = pk;
                }
            }

            bf16x8 vb[2][4];
            #pragma unroll
            for (int ks = 0; ks < 2; ++ks)
                #pragma unroll
                for (int ni = 0; ni < 4; ++ni)
                    vb[ks][ni] = *(const bf16x8*)(Vts + (ni * 16 + l) * 64 +
                                                  ((((ks << 2) + quad) ^ sw8) << 3));

            asm volatile("s_waitcnt lgkmcnt(0)" ::: "memory");

            #pragma unroll
            for (int ks = 0; ks < 2; ++ks) {
                bf16x8 pa[4];
                #pragma unroll
                for (int mi = 0; mi < 4; ++mi)
                    pa[mi] = *(const bf16x8*)(Pw + (mi * 16 + l) * 72 + ks * 32 + quad * 8);
                #pragma unroll
                for (int ni = 0; ni < 4; ++ni)
                    #pragma unroll
                    for (int mi = 0; mi < 4; ++mi)
                        O[mi][ni] = MFMA(pa[mi], vb[ks][ni], O[mi][ni]);
            }
        }
    }

    // ---------------- epilogue ----------------
    __syncthreads();
    float* epi = (float*)(smem + half * 16640);    // [64][65] f32 per q-half

    #pragma unroll
    for (int ni = 0; ni < 4; ++ni) {
        csum[ni] += __shfl_xor(csum[ni], 16, 64);
        csum[ni] += __shfl_xor(csum[ni], 32, 64);
    }

    if (sid == 1) {
        const float lam = lam_p[0];
        #pragma unroll
        for (int mi = 0; mi < 4; ++mi)
            #pragma unroll
            for (int r = 0; r < 4; ++r) {
                const float inv = lam / __shfl(csum[mi], quad * 4 + r, 64);
                const int row = mi * 16 + quad * 4 + r;
                #pragma unroll
                for (int ni = 0; ni < 4; ++ni)
                    epi[row * 65 + ni * 16 + l] = O[mi][ni][r] * inv;
            }
    }
    __syncthreads();

    if (sid == 0) {
        float sw[4];
        #pragma unroll
        for (int ni = 0; ni < 4; ++ni) sw[ni] = subln_w[ni * 16 + l];

        #pragma unroll
        for (int mi = 0; mi < 4; ++mi) {
            float inv1[4];
            #pragma unroll
            for (int r = 0; r < 4; ++r)
                inv1[r] = 1.0f / __shfl(csum[mi], quad * 4 + r, 64);

            float v[4][4]; float ssq[4] = {0.f, 0.f, 0.f, 0.f};
            #pragma unroll
            for (int ni = 0; ni < 4; ++ni)
                #pragma unroll
                for (int r = 0; r < 4; ++r) {
                    const int row = mi * 16 + quad * 4 + r;
                    const float x = O[mi][ni][r] * inv1[r] - epi[row * 65 + ni * 16 + l];
                    v[ni][r] = x;
                    ssq[r] += x * x;
                }
            #pragma unroll
            for (int r = 0; r < 4; ++r) {
                float s = ssq[r];
                s += __shfl_xor(s, 1, 64);
                s += __shfl_xor(s, 2, 64);
                s += __shfl_xor(s, 4, 64);
                s += __shfl_xor(s, 8, 64);
                ssq[r] = rsqrtf(s * (1.0f / 64.0f) + RMS_EPS) * ONE_MINUS_LAM_INIT;
            }
            #pragma unroll
            for (int ni = 0; ni < 4; ++ni)
                #pragma unroll
                for (int r = 0; r < 4; ++r) {
                    const int row = q0w + mi * 16 + quad * 4 + r;
                    attn_out[(size_t)row * HID_DIM + h * 64 + ni * 16 + l] =
                        (bf16)(v[ni][r] * ssq[r] * sw[ni]);
                }
        }
    }
}

// ---------------------------------------------------------------------------
// Workspace layout (bytes):
//   hsb   @ 0           8,388,608   hidden bf16
//   Wb    @ 8388608    41,943,040   Wq|Wk|Wv bf16
//   Wob   @ 50331648    8,388,608   Wo bf16
//   qkv   @ 58720256   41,943,040   bf16 [2048,10240]; reused as split-K
//                                   partials (2 x 16.8 MB fp32) for O-proj
//   Q1    @ 100663296   8,388,608
//   K1    @ 109051904   8,388,608
//   Q2    @ 117440512   8,388,608
//   K2    @ 125829120   8,388,608
//   Vt    @ 134217728   8,388,608
//   abuf  @ 142606336   8,388,608
//   lam   @ 150994944   4
// ---------------------------------------------------------------------------
extern "C" void kernel_launch(void* const* d_in, const int* in_sizes, int n_in,
                              void* d_out, int out_size, void* d_ws, size_t ws_size,
                              hipStream_t stream) {
    const float* hs  = (const float*)d_in[0];
    const float* Wq  = (const float*)d_in[1];
    const float* Wk  = (const float*)d_in[2];
    const float* Wv  = (const float*)d_in[3];
    const float* Wo  = (const float*)d_in[4];
    const float* lq1 = (const float*)d_in[5];
    const float* lk1 = (const float*)d_in[6];
    const float* lq2 = (const float*)d_in[7];
    const float* lk2 = (const float*)d_in[8];
    const float* slw = (const float*)d_in[9];

    if (ws_size < 151000000u) return;

    char* ws = (char*)d_ws;
    bf16*  hsb  = (bf16*)(ws);
    bf16*  Wb   = (bf16*)(ws + 8388608);
    bf16*  Wob  = (bf16*)(ws + 50331648);
    bf16*  qkv  = (bf16*)(ws + 58720256);
    float* part = (float*)(ws + 58720256);          // reuses qkv region
    bf16*  Q1b  = (bf16*)(ws + 100663296);
    bf16*  K1b  = (bf16*)(ws + 109051904);
    bf16*  Q2b  = (bf16*)(ws + 117440512);
    bf16*  K2b  = (bf16*)(ws + 125829120);
    bf16*  Vtb  = (bf16*)(ws + 134217728);
    bf16*  abuf = (bf16*)(ws + 142606336);
    float* lamp = (float*)(ws + 150994944);

    // 1) all conversions + lambda, one kernel
    cvt_all<<<28673, 256, 0, stream>>>(hs, Wq, Wk, Wv, Wo, lq1, lk1, lq2, lk2,
                                       hsb, Wb, Wob, lamp);

    // 2) fused QKV projection
    gemm_bt<1><<<dim3(QKV_N / 128, S_LEN / 128, 1), 256, 0, stream>>>(
        hsb, Wb, qkv, S_LEN, QKV_N, HID_DIM, HID_DIM);

    // 3) RoPE + head split
    rope_split<<<dim3(S_LEN / 64, NHEAD), 256, 0, stream>>>(qkv, Q1b, K1b, Q2b, K2b, Vtb);

    // 4) differential attention
    diff_attn<<<512, 256, 0, stream>>>(Q1b, K1b, Q2b, K2b, Vtb, lamp, slw, abuf);

    // 5) output projection, split-K=2 -> fp32 partials -> reduce to d_out
    gemm_bt<2><<<dim3(HID_DIM / 128, S_LEN / 128, 2), 256, 0, stream>>>(
        abuf, Wob, part, S_LEN, HID_DIM, HID_DIM, HID_DIM / 2);
    reduce_add<<<4096, 256, 0, stream>>>(part, (float*)d_out, S_LEN * HID_DIM);
}

// Round 6
// 361.622 us; speedup vs baseline: 1.6419x; 1.0214x over previous
//
#include <hip/hip_runtime.h>

// ---------------------------------------------------------------------------
// LlamaDifferentialAttentionBase on MI355X (gfx950)
// B=1, S=2048, HID=2048, H=32, D=64. All inputs fp32; output fp32.
// R6: RoPE + head-split + V-transpose fused into the QKV GEMM epilogue
//     (C computed transposed: d=row, s=col -> rope partner d^32 is in-lane
//     acc[wi^2], Q/K stores are bf16x4 along d, V stores transposed).
//     rope_split kernel and qkv intermediate eliminated.
// ---------------------------------------------------------------------------

typedef __bf16 bf16;
typedef __bf16 bf16x4 __attribute__((ext_vector_type(4)));
typedef __bf16 bf16x8 __attribute__((ext_vector_type(8)));
typedef float  f32x4  __attribute__((ext_vector_type(4)));

#define MFMA(a, b, c) __builtin_amdgcn_mfma_f32_16x16x32_bf16((a), (b), (c), 0, 0, 0)

#define S_LEN   2048
#define HID_DIM 2048
#define NHEAD   32
#define HD      64
#define QKV_N   10240                 // 4096 (q) + 4096 (k) + 2048 (v)
#define LAM_INIT 0.7836057665316245f  // 0.8 - 0.6*exp(-0.3*12)
#define ONE_MINUS_LAM_INIT 0.21639423346837553f
#define QSCALE  0.18033688011112042f  // (1/sqrt(64)) * log2(e)
#define RMS_EPS 1e-6f
#define L2T     0.4152410118609203f   // log2(10000)/32

// async global->LDS, 16B per lane; LDS dest = wave-uniform base + lane*16
__device__ __forceinline__ void gld16(const void* g, void* l) {
    __builtin_amdgcn_global_load_lds(
        (const __attribute__((address_space(1))) void*)g,
        (__attribute__((address_space(3))) void*)l, 16, 0, 0);
}

// ---------------------------------------------------------------------------
// Fused fp32->bf16 for all 5 tensors + lambda scalar (last block).
// ---------------------------------------------------------------------------
__global__ void cvt_all(const float* __restrict__ hs, const float* __restrict__ Wq,
                        const float* __restrict__ Wk, const float* __restrict__ Wv,
                        const float* __restrict__ Wo,
                        const float* __restrict__ lq1, const float* __restrict__ lk1,
                        const float* __restrict__ lq2, const float* __restrict__ lk2,
                        bf16* __restrict__ hsb, bf16* __restrict__ Wb,
                        bf16* __restrict__ Wob, float* __restrict__ lam_out) {
    const int bid = blockIdx.x;
    if (bid >= 28672) {               // lambda block
        const int t = threadIdx.x;
        if (t < 64) {
            float a = lq1[t] * lk1[t];
            float b = lq2[t] * lk2[t];
            #pragma unroll
            for (int off = 32; off > 0; off >>= 1) {
                a += __shfl_xor(a, off, 64);
                b += __shfl_xor(b, off, 64);
            }
            if (t == 0) lam_out[0] = expf(a) - expf(b) + LAM_INIT;
        }
        return;
    }
    const float* src; bf16* dst; int off;
    if      (bid <  4096) { src = hs; dst = hsb;            off = bid;         }
    else if (bid < 12288) { src = Wq; dst = Wb;             off = bid - 4096;  }
    else if (bid < 20480) { src = Wk; dst = Wb +  8388608;  off = bid - 12288; }
    else if (bid < 24576) { src = Wv; dst = Wb + 16777216;  off = bid - 20480; }
    else                  { src = Wo; dst = Wob;            off = bid - 24576; }
    const int i = off * 1024 + threadIdx.x * 4;
    float4 v = *(const float4*)(src + i);
    bf16x4 o = { (bf16)v.x, (bf16)v.y, (bf16)v.z, (bf16)v.w };
    *(bf16x4*)(dst + i) = o;
}

// ---------------------------------------------------------------------------
// Fused QKV GEMM + RoPE + head split + V transpose.
// C = hs @ W^T computed TRANSPOSED: MFMA(W_frag, hs_frag) -> C row = W-row
// (output col / head dim d), C col = hs-row (s). Fragment (wi,hi,r):
//   d_local = wi*16 + quad*4 + r,  s_local = hi*16 + l.
// RoPE partner d^32 = acc[wi^2] (same lane). i = d&31 = (wi&1)*16+quad*4+r,
// sign = (wi<2) ? -1 : +1. Q/K: bf16x4 store along d. V: Vt[h][d][s] scalar.
// 128x128 tile, BK=64, XOR-swizzled LDS staging (conflict-free), 4 waves.
// ---------------------------------------------------------------------------
__global__ __launch_bounds__(256, 3)
void qkv_rope_gemm(const bf16* __restrict__ A, const bf16* __restrict__ B,
                   bf16* __restrict__ Q1, bf16* __restrict__ Q2,
                   bf16* __restrict__ K1, bf16* __restrict__ K2,
                   bf16* __restrict__ Vt) {
    __shared__ __align__(16) bf16 As[128 * 64];
    __shared__ __align__(16) bf16 Bs[128 * 64];
    const int tid  = threadIdx.x;
    const int wave = tid >> 6, lane = tid & 63;
    const int wm = wave >> 1, wn = wave & 1;      // wm: s-half, wn: d-half
    const int l = lane & 15, quad = lane >> 4;
    const int m0 = blockIdx.y * 128, n0 = blockIdx.x * 128;

    f32x4 acc[4][4];                              // [wi (d)][hi (s)]
    #pragma unroll
    for (int i = 0; i < 4; ++i)
        #pragma unroll
        for (int j = 0; j < 4; ++j) acc[i][j] = (f32x4){0.f, 0.f, 0.f, 0.f};

    const int rr  = tid >> 3;
    const int csw = ((tid & 7) ^ (rr & 7)) * 8;
    const bf16* Ag = A + (size_t)(m0 + rr) * HID_DIM + csw;
    const bf16* Bg = B + (size_t)(n0 + rr) * HID_DIM + csw;

    for (int kt = 0; kt < HID_DIM; kt += 64) {
        __syncthreads();
        #pragma unroll
        for (int j = 0; j < 4; ++j) {
            gld16(Ag + (size_t)(32 * j) * HID_DIM + kt, As + j * 2048 + tid * 8);
            gld16(Bg + (size_t)(32 * j) * HID_DIM + kt, Bs + j * 2048 + tid * 8);
        }
        __syncthreads();

        #pragma unroll
        for (int ks = 0; ks < 2; ++ks) {
            const int co = (((ks << 2) | quad) ^ (l & 7)) << 3;
            bf16x8 hf[4], wf[4];
            #pragma unroll
            for (int hi = 0; hi < 4; ++hi)
                hf[hi] = *(const bf16x8*)(As + (wm * 64 + hi * 16 + l) * 64 + co);
            #pragma unroll
            for (int wi = 0; wi < 4; ++wi)
                wf[wi] = *(const bf16x8*)(Bs + (wn * 64 + wi * 16 + l) * 64 + co);
            #pragma unroll
            for (int wi = 0; wi < 4; ++wi)
                #pragma unroll
                for (int hi = 0; hi < 4; ++hi)
                    acc[wi][hi] = MFMA(wf[wi], hf[hi], acc[wi][hi]);  // row=d, col=s
        }
    }

    // ---- epilogue: RoPE + store ----
    const int c = n0 + wn * 64;                   // global qkv column base
    const int sbase = m0 + wm * 64;
    bf16* dst; int off; float scale = 1.0f; bool isv = false;
    if      (c < 2048) { dst = Q1; off = c;        scale = QSCALE; }
    else if (c < 4096) { dst = Q2; off = c - 2048; scale = QSCALE; }
    else if (c < 6144) { dst = K1; off = c - 4096; }
    else if (c < 8192) { dst = K2; off = c - 6144; }
    else               { isv = true; off = c - 8192; }
    const int h = off >> 6;                       // off is 64-aligned

    if (!isv) {
        float invf[2][4];
        #pragma unroll
        for (int p = 0; p < 2; ++p)
            #pragma unroll
            for (int r = 0; r < 4; ++r)
                invf[p][r] = exp2f(-(float)(p * 16 + quad * 4 + r) * L2T);

        #pragma unroll
        for (int hi = 0; hi < 4; ++hi) {
            const float s = (float)(sbase + hi * 16 + l);
            float cs[2][4], sn[2][4];
            #pragma unroll
            for (int p = 0; p < 2; ++p)
                #pragma unroll
                for (int r = 0; r < 4; ++r) {
                    const float ang = s * invf[p][r];
                    cs[p][r] = __cosf(ang);
                    sn[p][r] = __sinf(ang);
                }
            bf16* rowp = dst + ((size_t)h * S_LEN + sbase + hi * 16 + l) * HD + quad * 4;
            #pragma unroll
            for (int wi = 0; wi < 4; ++wi) {
                const int p = wi & 1;
                const float sign = (wi < 2) ? -1.0f : 1.0f;
                bf16x4 o;
                #pragma unroll
                for (int r = 0; r < 4; ++r)
                    o[r] = (bf16)((acc[wi][hi][r] * cs[p][r] +
                                   sign * acc[wi ^ 2][hi][r] * sn[p][r]) * scale);
                *(bf16x4*)(rowp + wi * 16) = o;
            }
        }
    } else {
        #pragma unroll
        for (int wi = 0; wi < 4; ++wi)
            #pragma unroll
            for (int r = 0; r < 4; ++r) {
                bf16* vrow = Vt + ((size_t)h * HD + wi * 16 + quad * 4 + r) * S_LEN + sbase;
                #pragma unroll
                for (int hi = 0; hi < 4; ++hi)
                    vrow[hi * 16 + l] = (bf16)acc[wi][hi][r];
            }
    }
}

// ---------------------------------------------------------------------------
// GEMM: C[M,N] = A[M,K] * B[N,K]^T, split-K partials (O-proj).
// ---------------------------------------------------------------------------
__global__ __launch_bounds__(256, 3)
void gemm_bt_splitk(const bf16* __restrict__ A, const bf16* __restrict__ B,
                    float* __restrict__ Cout, int M, int N, int K_total, int K_part) {
    __shared__ __align__(16) bf16 As[128 * 64];
    __shared__ __align__(16) bf16 Bs[128 * 64];
    const int tid  = threadIdx.x;
    const int wave = tid >> 6, lane = tid & 63;
    const int wm = wave >> 1, wn = wave & 1;
    const int l = lane & 15, quad = lane >> 4;
    const int m0 = blockIdx.y * 128, n0 = blockIdx.x * 128;
    const int kz = blockIdx.z * K_part;

    f32x4 acc[4][4];
    #pragma unroll
    for (int i = 0; i < 4; ++i)
        #pragma unroll
        for (int j = 0; j < 4; ++j) acc[i][j] = (f32x4){0.f, 0.f, 0.f, 0.f};

    const int rr  = tid >> 3;
    const int csw = ((tid & 7) ^ (rr & 7)) * 8;
    const bf16* Ag = A + (size_t)(m0 + rr) * K_total + kz + csw;
    const bf16* Bg = B + (size_t)(n0 + rr) * K_total + kz + csw;

    for (int kt = 0; kt < K_part; kt += 64) {
        __syncthreads();
        #pragma unroll
        for (int j = 0; j < 4; ++j) {
            gld16(Ag + (size_t)(32 * j) * K_total + kt, As + j * 2048 + tid * 8);
            gld16(Bg + (size_t)(32 * j) * K_total + kt, Bs + j * 2048 + tid * 8);
        }
        __syncthreads();

        #pragma unroll
        for (int ks = 0; ks < 2; ++ks) {
            const int co = (((ks << 2) | quad) ^ (l & 7)) << 3;
            bf16x8 af[4], bfr[4];
            #pragma unroll
            for (int mi = 0; mi < 4; ++mi)
                af[mi] = *(const bf16x8*)(As + (wm * 64 + mi * 16 + l) * 64 + co);
            #pragma unroll
            for (int ni = 0; ni < 4; ++ni)
                bfr[ni] = *(const bf16x8*)(Bs + (wn * 64 + ni * 16 + l) * 64 + co);
            #pragma unroll
            for (int mi = 0; mi < 4; ++mi)
                #pragma unroll
                for (int ni = 0; ni < 4; ++ni)
                    acc[mi][ni] = MFMA(af[mi], bfr[ni], acc[mi][ni]);
        }
    }

    float* Pf = Cout + (size_t)blockIdx.z * M * N;
    #pragma unroll
    for (int mi = 0; mi < 4; ++mi)
        #pragma unroll
        for (int ni = 0; ni < 4; ++ni)
            #pragma unroll
            for (int r = 0; r < 4; ++r) {
                const int row = m0 + wm * 64 + mi * 16 + quad * 4 + r;
                const int col = n0 + wn * 64 + ni * 16 + l;
                Pf[(size_t)row * N + col] = acc[mi][ni][r];
            }
}

// split-K reduce: out[i] = p[i] + p[n+i]  (fp32, float4)
__global__ void reduce_add(const float* __restrict__ p, float* __restrict__ out, int n) {
    const int i = (blockIdx.x * 256 + threadIdx.x) * 4;
    float4 a = *(const float4*)(p + i);
    float4 b = *(const float4*)(p + n + i);
    float4 o = { a.x + b.x, a.y + b.y, a.z + b.z, a.w + b.w };
    *(float4*)(out + i) = o;
}

// ---------------------------------------------------------------------------
// Differential flash attention (unchanged from R5)
// ---------------------------------------------------------------------------
__global__ __launch_bounds__(256, 2)
void diff_attn(const bf16* __restrict__ Q1, const bf16* __restrict__ K1,
               const bf16* __restrict__ Q2, const bf16* __restrict__ K2,
               const bf16* __restrict__ Vt, const float* __restrict__ lam_p,
               const float* __restrict__ subln_w, bf16* __restrict__ attn_out) {
    const int bid  = blockIdx.x;
    const int h    = (bid >> 1) & 31;
    const int idx  = bid >> 6;
    const int qb   = (bid & 1) ? idx : (15 - idx);
    const int q0   = qb * 128;
    const int tid  = threadIdx.x;
    const int wave = tid >> 6, lane = tid & 63;
    const int sid  = wave >> 1, half = wave & 1;
    const int l    = lane & 15, quad = lane >> 4;
    const int q0w  = q0 + half * 64;

    __shared__ __align__(16) char smem[61440];
    bf16* K1s = (bf16*)smem;
    bf16* K2s = (bf16*)(smem + 8192);
    bf16* Vts = (bf16*)(smem + 16384);
    bf16* Pw  = (bf16*)(smem + 24576 + wave * 9216);

    const bf16* Qh  = (sid ? Q2 : Q1) + ((size_t)h * S_LEN + q0w) * HD;
    const bf16* K1g = K1 + (size_t)h * S_LEN * HD;
    const bf16* K2g = K2 + (size_t)h * S_LEN * HD;
    const bf16* Vtg = Vt + (size_t)h * HD * S_LEN;
    const bf16* Ksm = sid ? K2s : K1s;

    const int rr  = tid >> 3;
    const int csw = ((tid & 7) ^ (rr & 7)) * 8;
    bf16* l1 = K1s + tid * 8;
    bf16* l2 = K2s + tid * 8;
    bf16* lv = Vts + tid * 8;

    bf16x8 qf[4][2];
    #pragma unroll
    for (int ni = 0; ni < 4; ++ni)
        #pragma unroll
        for (int ks = 0; ks < 2; ++ks)
            qf[ni][ks] = *(const bf16x8*)(Qh + (ni * 16 + l) * HD + ks * 32 + quad * 8);

    f32x4 O[4][4];
    #pragma unroll
    for (int mi = 0; mi < 4; ++mi)
        #pragma unroll
        for (int ni = 0; ni < 4; ++ni)
            O[mi][ni] = (f32x4){0.f, 0.f, 0.f, 0.f};
    float csum[4] = {0.f, 0.f, 0.f, 0.f};

    const int T = 2 * qb + 2;
    const int sw8 = l & 7;
    for (int t = 0; t < T; ++t) {
        const int kv0 = t * 64;
        __syncthreads();
        {
            const bf16* k1p = K1g + (size_t)(kv0 + rr) * HD + csw;
            const bf16* k2p = K2g + (size_t)(kv0 + rr) * HD + csw;
            const bf16* vtp = Vtg + (size_t)rr * S_LEN + kv0 + csw;
            gld16(k1p, l1);
            gld16(k1p + (size_t)32 * HD, l1 + 2048);
            gld16(k2p, l2);
            gld16(k2p + (size_t)32 * HD, l2 + 2048);
            gld16(vtp, lv);
            gld16(vtp + (size_t)32 * S_LEN, lv + 2048);
        }
        __syncthreads();

        if (kv0 <= q0w) {
            const bool diag = (kv0 == q0w);

            #pragma unroll
            for (int mi = 0; mi < 4; ++mi) {
                const int krow = (mi * 16 + l) * 64;
                bf16x8 ka0 = *(const bf16x8*)(Ksm + krow + ((quad ^ sw8) << 3));
                bf16x8 ka1 = *(const bf16x8*)(Ksm + krow + (((4 + quad) ^ sw8) << 3));
                #pragma unroll
                for (int ni = 0; ni < 4; ++ni) {
                    f32x4 c = (f32x4){0.f, 0.f, 0.f, 0.f};
                    c = MFMA(ka0, qf[ni][0], c);
                    c = MFMA(ka1, qf[ni][1], c);
                    bf16x4 pk;
                    float lsum = 0.f;
                    #pragma unroll
                    for (int r = 0; r < 4; ++r) {
                        float p = __builtin_amdgcn_exp2f(c[r]);
                        if (diag && (mi * 16 + quad * 4 + r > ni * 16 + l)) p = 0.f;
                        lsum += p;
                        pk[r] = (bf16)p;
                    }
                    csum[ni] += lsum;
                    *(bf16x4*)(Pw + (ni * 16 + l) * 72 + mi * 16 + quad * 4) = pk;
                }
            }

            bf16x8 vb[2][4];
            #pragma unroll
            for (int ks = 0; ks < 2; ++ks)
                #pragma unroll
                for (int ni = 0; ni < 4; ++ni)
                    vb[ks][ni] = *(const bf16x8*)(Vts + (ni * 16 + l) * 64 +
                                                  ((((ks << 2) + quad) ^ sw8) << 3));

            asm volatile("s_waitcnt lgkmcnt(0)" ::: "memory");

            #pragma unroll
            for (int ks = 0; ks < 2; ++ks) {
                bf16x8 pa[4];
                #pragma unroll
                for (int mi = 0; mi < 4; ++mi)
                    pa[mi] = *(const bf16x8*)(Pw + (mi * 16 + l) * 72 + ks * 32 + quad * 8);
                #pragma unroll
                for (int ni = 0; ni < 4; ++ni)
                    #pragma unroll
                    for (int mi = 0; mi < 4; ++mi)
                        O[mi][ni] = MFMA(pa[mi], vb[ks][ni], O[mi][ni]);
            }
        }
    }

    // ---------------- epilogue ----------------
    __syncthreads();
    float* epi = (float*)(smem + half * 16640);

    #pragma unroll
    for (int ni = 0; ni < 4; ++ni) {
        csum[ni] += __shfl_xor(csum[ni], 16, 64);
        csum[ni] += __shfl_xor(csum[ni], 32, 64);
    }

    if (sid == 1) {
        const float lam = lam_p[0];
        #pragma unroll
        for (int mi = 0; mi < 4; ++mi)
            #pragma unroll
            for (int r = 0; r < 4; ++r) {
                const float inv = lam / __shfl(csum[mi], quad * 4 + r, 64);
                const int row = mi * 16 + quad * 4 + r;
                #pragma unroll
                for (int ni = 0; ni < 4; ++ni)
                    epi[row * 65 + ni * 16 + l] = O[mi][ni][r] * inv;
            }
    }
    __syncthreads();

    if (sid == 0) {
        float sw[4];
        #pragma unroll
        for (int ni = 0; ni < 4; ++ni) sw[ni] = subln_w[ni * 16 + l];

        #pragma unroll
        for (int mi = 0; mi < 4; ++mi) {
            float inv1[4];
            #pragma unroll
            for (int r = 0; r < 4; ++r)
                inv1[r] = 1.0f / __shfl(csum[mi], quad * 4 + r, 64);

            float v[4][4]; float ssq[4] = {0.f, 0.f, 0.f, 0.f};
            #pragma unroll
            for (int ni = 0; ni < 4; ++ni)
                #pragma unroll
                for (int r = 0; r < 4; ++r) {
                    const int row = mi * 16 + quad * 4 + r;
                    const float x = O[mi][ni][r] * inv1[r] - epi[row * 65 + ni * 16 + l];
                    v[ni][r] = x;
                    ssq[r] += x * x;
                }
            #pragma unroll
            for (int r = 0; r < 4; ++r) {
                float s = ssq[r];
                s += __shfl_xor(s, 1, 64);
                s += __shfl_xor(s, 2, 64);
                s += __shfl_xor(s, 4, 64);
                s += __shfl_xor(s, 8, 64);
                ssq[r] = rsqrtf(s * (1.0f / 64.0f) + RMS_EPS) * ONE_MINUS_LAM_INIT;
            }
            #pragma unroll
            for (int ni = 0; ni < 4; ++ni)
                #pragma unroll
                for (int r = 0; r < 4; ++r) {
                    const int row = q0w + mi * 16 + quad * 4 + r;
                    attn_out[(size_t)row * HID_DIM + h * 64 + ni * 16 + l] =
                        (bf16)(v[ni][r] * ssq[r] * sw[ni]);
                }
        }
    }
}

// ---------------------------------------------------------------------------
// Workspace layout (bytes):
//   hsb   @ 0           8,388,608   hidden bf16
//   Wb    @ 8388608    41,943,040   Wq|Wk|Wv bf16
//   Wob   @ 50331648    8,388,608   Wo bf16
//   part  @ 58720256   33,554,432   O-proj split-K fp32 partials (2x)
//   Q1    @ 100663296   8,388,608
//   K1    @ 109051904   8,388,608
//   Q2    @ 117440512   8,388,608
//   K2    @ 125829120   8,388,608
//   Vt    @ 134217728   8,388,608
//   abuf  @ 142606336   8,388,608
//   lam   @ 150994944   4
// ---------------------------------------------------------------------------
extern "C" void kernel_launch(void* const* d_in, const int* in_sizes, int n_in,
                              void* d_out, int out_size, void* d_ws, size_t ws_size,
                              hipStream_t stream) {
    const float* hs  = (const float*)d_in[0];
    const float* Wq  = (const float*)d_in[1];
    const float* Wk  = (const float*)d_in[2];
    const float* Wv  = (const float*)d_in[3];
    const float* Wo  = (const float*)d_in[4];
    const float* lq1 = (const float*)d_in[5];
    const float* lk1 = (const float*)d_in[6];
    const float* lq2 = (const float*)d_in[7];
    const float* lk2 = (const float*)d_in[8];
    const float* slw = (const float*)d_in[9];

    if (ws_size < 151000000u) return;

    char* ws = (char*)d_ws;
    bf16*  hsb  = (bf16*)(ws);
    bf16*  Wb   = (bf16*)(ws + 8388608);
    bf16*  Wob  = (bf16*)(ws + 50331648);
    float* part = (float*)(ws + 58720256);
    bf16*  Q1b  = (bf16*)(ws + 100663296);
    bf16*  K1b  = (bf16*)(ws + 109051904);
    bf16*  Q2b  = (bf16*)(ws + 117440512);
    bf16*  K2b  = (bf16*)(ws + 125829120);
    bf16*  Vtb  = (bf16*)(ws + 134217728);
    bf16*  abuf = (bf16*)(ws + 142606336);
    float* lamp = (float*)(ws + 150994944);

    // 1) conversions + lambda
    cvt_all<<<28673, 256, 0, stream>>>(hs, Wq, Wk, Wv, Wo, lq1, lk1, lq2, lk2,
                                       hsb, Wb, Wob, lamp);

    // 2) fused QKV projection + RoPE + split + V transpose
    qkv_rope_gemm<<<dim3(QKV_N / 128, S_LEN / 128), 256, 0, stream>>>(
        hsb, Wb, Q1b, Q2b, K1b, K2b, Vtb);

    // 3) differential attention
    diff_attn<<<512, 256, 0, stream>>>(Q1b, K1b, Q2b, K2b, Vtb, lamp, slw, abuf);

    // 4) output projection, split-K=2 -> fp32 partials -> reduce to d_out
    gemm_bt_splitk<<<dim3(HID_DIM / 128, S_LEN / 128, 2), 256, 0, stream>>>(
        abuf, Wob, part, S_LEN, HID_DIM, HID_DIM, HID_DIM / 2);
    reduce_add<<<4096, 256, 0, stream>>>(part, (float*)d_out, S_LEN * HID_DIM);
}